// Round 1
// baseline (398.676 us; speedup 1.0000x reference)
//
#include <hip/hip_runtime.h>
#include <hip/hip_bf16.h>
#include <math.h>

#define NN 50000
#define NE 400000

typedef __attribute__((ext_vector_type(8))) short bf16x8;
typedef __attribute__((ext_vector_type(4))) float f32x4;

// ---------------- helpers ----------------
__device__ __forceinline__ float lrelu(float v){ return v > 0.f ? v : 0.2f*v; }
__device__ __forceinline__ float elu1(float v){ return v > 0.f ? v : expm1f(v); }
__device__ __forceinline__ float bflo(unsigned int u){ return __uint_as_float(u << 16); }
__device__ __forceinline__ float bfhi(unsigned int u){ return __uint_as_float(u & 0xffff0000u); }
__device__ __forceinline__ unsigned short f2bf(float f){
  __hip_bfloat16 h = __float2bfloat16(f);
  return *(unsigned short*)&h;
}
__device__ __forceinline__ unsigned int pack2(float lo, float hi){
  return (unsigned int)f2bf(lo) | ((unsigned int)f2bf(hi) << 16);
}

// ---------------- CSR build ----------------
__global__ void k_count(const int* __restrict__ col, int* __restrict__ cnt, int E){
  int e = blockIdx.x*blockDim.x + threadIdx.x;
  if(e < E) atomicAdd(&cnt[col[e]], 1);
}

__global__ void k_alloc(const int* __restrict__ cnt, int* __restrict__ offs,
                        float* __restrict__ dis, float* __restrict__ invc,
                        int* __restrict__ total, int N){
  int i = blockIdx.x*blockDim.x + threadIdx.x;
  int lane = threadIdx.x & 63;
  int v = (i < N) ? cnt[i] : 0;
  int x = v;
  #pragma unroll
  for(int d = 1; d < 64; d <<= 1){ int t = __shfl_up(x, d, 64); if(lane >= d) x += t; }
  int base = 0;
  if(lane == 63 && x > 0) base = atomicAdd(total, x);
  base = __shfl(base, 63, 64);
  if(i < N){
    offs[i] = base + x - v;
    dis[i]  = 1.0f / sqrtf((float)(v + 1));
    invc[i] = 1.0f / fmaxf((float)v, 1.0f);
  }
}

__global__ void k_fill(const int* __restrict__ row, const int* __restrict__ col,
                       const int* __restrict__ offs, int* __restrict__ cursor,
                       int* __restrict__ csr, int E){
  int e = blockIdx.x*blockDim.x + threadIdx.x;
  if(e < E){
    int c = col[e];
    int pos = offs[c] + atomicAdd(&cursor[c], 1);
    csr[pos] = row[e];
  }
}

// ---------------- pack weights to bf16, B-fragment layout [n][k] ----------------
struct PKS { const float* src; unsigned short* dst; int kshift; int ldw; int col0; };
struct PKP { PKS s[11]; };

__global__ void k_packw(PKP p){
  PKS s = p.s[blockIdx.x];
  int K = 1 << s.kshift;
  int total = K << 6;            // 64 output columns (n) x K
  for(int idx = threadIdx.x; idx < total; idx += 256){
    int n = idx >> s.kshift, k = idx & (K - 1);
    s.dst[idx] = f2bf(s.src[(size_t)k*s.ldw + s.col0 + n]);
  }
}

// ---------------- cast x -> bf16 + column sums for gate ----------------
__global__ void k_castsum(const float* __restrict__ x, unsigned short* __restrict__ xb,
                          float* __restrict__ gsum, int N){
  __shared__ float part[4][64];
  int lane = threadIdx.x & 63, w = threadIdx.x >> 6;
  float s = 0.f;
  for(int r = blockIdx.x*4 + w; r < N; r += gridDim.x*4){
    float v = x[(size_t)r*64 + lane];
    xb[(size_t)r*64 + lane] = f2bf(v);
    s += v;
  }
  part[w][lane] = s;
  __syncthreads();
  if(w == 0) atomicAdd(&gsum[lane], part[0][lane]+part[1][lane]+part[2][lane]+part[3][lane]);
}

__global__ void k_gate(const float* __restrict__ gsum,
                       const float* __restrict__ w1, const float* __restrict__ b1,
                       const float* __restrict__ w2, const float* __restrict__ b2,
                       float* __restrict__ gatew){
  __shared__ float g[64]; __shared__ float hid[64]; __shared__ float lg[3];
  int t = threadIdx.x;
  g[t] = gsum[t] * (1.0f/(float)NN);
  __syncthreads();
  float acc = b1[t];
  for(int i = 0; i < 64; i++) acc += g[i]*w1[i*64 + t];
  hid[t] = fmaxf(acc, 0.f);
  __syncthreads();
  if(t < 3){
    float a = b2[t];
    for(int j = 0; j < 64; j++) a += hid[j]*w2[j*3 + t];
    lg[t] = a;
  }
  __syncthreads();
  if(t == 0){
    float m = fmaxf(lg[0], fmaxf(lg[1], lg[2]));
    float e0 = expf(lg[0]-m), e1 = expf(lg[1]-m), e2 = expf(lg[2]-m);
    float s = e0 + e1 + e2;
    gatew[0] = e0/s; gatew[1] = e1/s; gatew[2] = e2/s;
  }
}

// ---------------- fold GAT1 attention vectors through W ----------------
__global__ void k_fold1(const float* __restrict__ w1, const float* __restrict__ as,
                        const float* __restrict__ ad, float* __restrict__ wsd){
  int t = threadIdx.x;            // 256
  int k = t & 63, h = t >> 6;
  float ssrc = 0.f, sdst = 0.f;
  for(int c = 0; c < 64; c++){
    float w = w1[k*256 + h*64 + c];
    ssrc += w * as[h*64 + c];
    sdst += w * ad[h*64 + c];
  }
  wsd[k*8 + h] = ssrc;
  wsd[k*8 + 4 + h] = sdst;
}

// ---------------- asrc1/adst1 = xb @ Wsd  (16 lanes per node) ----------------
__global__ void k_attdotx(const unsigned short* __restrict__ xb, const float* __restrict__ wsd,
                          float* __restrict__ asrc, float* __restrict__ adst, int N){
  __shared__ float ws[64*8];
  int tid = threadIdx.x;
  ws[tid] = wsd[tid];
  ws[tid + 256] = wsd[tid + 256];
  __syncthreads();
  int node = blockIdx.x*16 + (tid >> 4);
  int l = tid & 15;
  if(node >= N) return;
  uint2 u = *(const uint2*)&xb[(size_t)node*64 + l*4];
  float v0 = bflo(u.x), v1 = bfhi(u.x), v2 = bflo(u.y), v3 = bfhi(u.y);
  float s[8];
  #pragma unroll
  for(int h = 0; h < 8; h++){
    s[h] = v0*ws[(l*4+0)*8+h] + v1*ws[(l*4+1)*8+h] + v2*ws[(l*4+2)*8+h] + v3*ws[(l*4+3)*8+h];
  }
  #pragma unroll
  for(int d = 8; d >= 1; d >>= 1){
    #pragma unroll
    for(int h = 0; h < 8; h++) s[h] += __shfl_xor(s[h], d, 16);
  }
  if(l == 0){
    float4 o1; o1.x = s[0]; o1.y = s[1]; o1.z = s[2]; o1.w = s[3];
    float4 o2; o2.x = s[4]; o2.y = s[5]; o2.z = s[6]; o2.w = s[7];
    *(float4*)&asrc[node*4] = o1;
    *(float4*)&adst[node*4] = o2;
  }
}

// ---------------- GAT edge weights ----------------
__global__ void k_edgew1(const float* __restrict__ asrc, const float* __restrict__ adst,
                         const int* __restrict__ offs, const int* __restrict__ cnt,
                         const int* __restrict__ csr,
                         float* __restrict__ wvE, float* __restrict__ rdenN,
                         float* __restrict__ wvS, int N){
  int node = blockIdx.x*4 + (threadIdx.x >> 6);
  int lane = threadIdx.x & 63;
  if(node >= N) return;
  float4 ad = *(const float4*)&adst[node*4];
  float a0 = 0.f, a1 = 0.f, a2 = 0.f, a3 = 0.f;
  int e0 = offs[node], e1 = e0 + cnt[node];
  for(int e = e0 + lane; e < e1; e += 64){
    int s = csr[e];
    float4 as = *(const float4*)&asrc[s*4];
    float4 w;
    w.x = expf(lrelu(as.x + ad.x));
    w.y = expf(lrelu(as.y + ad.y));
    w.z = expf(lrelu(as.z + ad.z));
    w.w = expf(lrelu(as.w + ad.w));
    a0 += w.x; a1 += w.y; a2 += w.z; a3 += w.w;
    *(float4*)&wvE[(size_t)e*4] = w;
  }
  #pragma unroll
  for(int d = 32; d >= 1; d >>= 1){
    a0 += __shfl_xor(a0, d, 64); a1 += __shfl_xor(a1, d, 64);
    a2 += __shfl_xor(a2, d, 64); a3 += __shfl_xor(a3, d, 64);
  }
  float4 asl = *(const float4*)&asrc[node*4];
  float4 ws;
  ws.x = expf(lrelu(asl.x + ad.x));
  ws.y = expf(lrelu(asl.y + ad.y));
  ws.z = expf(lrelu(asl.z + ad.z));
  ws.w = expf(lrelu(asl.w + ad.w));
  if(lane == 0){
    float4 rd;
    rd.x = 1.0f/(a0 + ws.x); rd.y = 1.0f/(a1 + ws.y);
    rd.z = 1.0f/(a2 + ws.z); rd.w = 1.0f/(a3 + ws.w);
    *(float4*)&rdenN[node*4] = rd;
    *(float4*)&wvS[node*4] = ws;
  }
}

__global__ void k_edgew2(const float* __restrict__ asrc, const float* __restrict__ adst,
                         const int* __restrict__ offs, const int* __restrict__ cnt,
                         const int* __restrict__ csr,
                         float* __restrict__ wvE, float* __restrict__ rdenN,
                         float* __restrict__ wvS, int N){
  int node = blockIdx.x*4 + (threadIdx.x >> 6);
  int lane = threadIdx.x & 63;
  if(node >= N) return;
  float ad = adst[node];
  float acc = 0.f;
  int e0 = offs[node], e1 = e0 + cnt[node];
  for(int e = e0 + lane; e < e1; e += 64){
    float w = expf(lrelu(asrc[csr[e]] + ad));
    acc += w;
    wvE[e] = w;
  }
  #pragma unroll
  for(int d = 32; d >= 1; d >>= 1) acc += __shfl_xor(acc, d, 64);
  float ws = expf(lrelu(asrc[node] + ad));
  if(lane == 0){
    rdenN[node] = 1.0f/(acc + ws);
    wvS[node] = ws;
  }
}

// ---------------- layer-1 one-pass pre-aggregation over xb ----------------
__global__ void k_aggx(const unsigned short* __restrict__ xb,
                       const float* __restrict__ wvE, const float* __restrict__ rden,
                       const float* __restrict__ wvS,
                       const float* __restrict__ dis, const float* __restrict__ invc,
                       const int* __restrict__ offs, const int* __restrict__ cnt,
                       const int* __restrict__ csr,
                       unsigned short* __restrict__ z, unsigned short* __restrict__ agcnx,
                       unsigned short* __restrict__ asagex, int N){
  int node = blockIdx.x*4 + (threadIdx.x >> 6);
  int lane = threadIdx.x & 63;
  if(node >= N) return;
  int half = lane >> 5, subl = lane & 31;      // subl*2, subl*2+1 channels
  float zg[4][2] = {{0,0},{0,0},{0,0},{0,0}};
  float gg[2] = {0,0}, ssv[2] = {0,0};
  int e0 = offs[node], e1 = e0 + cnt[node];
  #pragma unroll 2
  for(int e = e0 + half; e < e1; e += 2){
    int s = csr[e];
    float4 w4 = *(const float4*)&wvE[(size_t)e*4];
    float ds = dis[s];
    unsigned int u = *(const unsigned int*)&xb[(size_t)s*64 + subl*2];
    float xl = bflo(u), xh = bfhi(u);
    zg[0][0] = fmaf(w4.x, xl, zg[0][0]); zg[0][1] = fmaf(w4.x, xh, zg[0][1]);
    zg[1][0] = fmaf(w4.y, xl, zg[1][0]); zg[1][1] = fmaf(w4.y, xh, zg[1][1]);
    zg[2][0] = fmaf(w4.z, xl, zg[2][0]); zg[2][1] = fmaf(w4.z, xh, zg[2][1]);
    zg[3][0] = fmaf(w4.w, xl, zg[3][0]); zg[3][1] = fmaf(w4.w, xh, zg[3][1]);
    gg[0] = fmaf(ds, xl, gg[0]); gg[1] = fmaf(ds, xh, gg[1]);
    ssv[0] += xl; ssv[1] += xh;
  }
  #pragma unroll
  for(int h = 0; h < 4; h++){
    zg[h][0] += __shfl_xor(zg[h][0], 32, 64);
    zg[h][1] += __shfl_xor(zg[h][1], 32, 64);
  }
  gg[0] += __shfl_xor(gg[0], 32, 64); gg[1] += __shfl_xor(gg[1], 32, 64);
  ssv[0] += __shfl_xor(ssv[0], 32, 64); ssv[1] += __shfl_xor(ssv[1], 32, 64);
  if(half == 0){
    unsigned int un = *(const unsigned int*)&xb[(size_t)node*64 + subl*2];
    float xl = bflo(un), xh = bfhi(un);
    float4 ws4 = *(const float4*)&wvS[node*4];
    float4 rd4 = *(const float4*)&rden[node*4];
    unsigned int* zp = (unsigned int*)&z[(size_t)node*256 + subl*2];
    zp[0]   = pack2((zg[0][0] + ws4.x*xl)*rd4.x, (zg[0][1] + ws4.x*xh)*rd4.x);
    zp[32]  = pack2((zg[1][0] + ws4.y*xl)*rd4.y, (zg[1][1] + ws4.y*xh)*rd4.y);
    zp[64]  = pack2((zg[2][0] + ws4.z*xl)*rd4.z, (zg[2][1] + ws4.z*xh)*rd4.z);
    zp[96]  = pack2((zg[3][0] + ws4.w*xl)*rd4.w, (zg[3][1] + ws4.w*xh)*rd4.w);
    float dc = dis[node], ic = invc[node];
    *(unsigned int*)&agcnx[(size_t)node*64 + subl*2] =
        pack2(dc*fmaf(dc, xl, gg[0]), dc*fmaf(dc, xh, gg[1]));
    *(unsigned int*)&asagex[(size_t)node*64 + subl*2] = pack2(ssv[0]*ic, ssv[1]*ic);
  }
}

// ---------------- layer-2 one-pass pre-aggregation over a1 / s1 / h2 ----------------
__global__ void k_aggf(const unsigned short* __restrict__ a1, const unsigned short* __restrict__ s1,
                       const unsigned short* __restrict__ h2,
                       const float* __restrict__ wvE, const float* __restrict__ rden,
                       const float* __restrict__ wvS,
                       const float* __restrict__ dis, const float* __restrict__ invc,
                       const int* __restrict__ offs, const int* __restrict__ cnt,
                       const int* __restrict__ csr,
                       unsigned short* __restrict__ A2agg, unsigned short* __restrict__ S2agg,
                       unsigned short* __restrict__ T2, int N){
  int node = blockIdx.x*4 + (threadIdx.x >> 6);
  int lane = threadIdx.x & 63;
  if(node >= N) return;
  int half = lane >> 5, subl = lane & 31;
  float aa[2] = {0,0}, ss[2] = {0,0}, tt[2] = {0,0};
  int e0 = offs[node], e1 = e0 + cnt[node];
  #pragma unroll 2
  for(int e = e0 + half; e < e1; e += 2){
    int s = csr[e];
    float ds = dis[s];
    float wv = wvE[e];
    unsigned int ua = *(const unsigned int*)&a1[(size_t)s*64 + subl*2];
    unsigned int us = *(const unsigned int*)&s1[(size_t)s*64 + subl*2];
    unsigned int uh = *(const unsigned int*)&h2[(size_t)s*64 + subl*2];
    aa[0] = fmaf(ds, bflo(ua), aa[0]); aa[1] = fmaf(ds, bfhi(ua), aa[1]);
    ss[0] += bflo(us); ss[1] += bfhi(us);
    tt[0] = fmaf(wv, bflo(uh), tt[0]); tt[1] = fmaf(wv, bfhi(uh), tt[1]);
  }
  aa[0] += __shfl_xor(aa[0], 32, 64); aa[1] += __shfl_xor(aa[1], 32, 64);
  ss[0] += __shfl_xor(ss[0], 32, 64); ss[1] += __shfl_xor(ss[1], 32, 64);
  tt[0] += __shfl_xor(tt[0], 32, 64); tt[1] += __shfl_xor(tt[1], 32, 64);
  if(half == 0){
    unsigned int uan = *(const unsigned int*)&a1[(size_t)node*64 + subl*2];
    unsigned int uhn = *(const unsigned int*)&h2[(size_t)node*64 + subl*2];
    float dc = dis[node], ic = invc[node];
    float rd = rden[node], wss = wvS[node];
    *(unsigned int*)&A2agg[(size_t)node*64 + subl*2] =
        pack2(dc*fmaf(dc, bflo(uan), aa[0]), dc*fmaf(dc, bfhi(uan), aa[1]));
    *(unsigned int*)&S2agg[(size_t)node*64 + subl*2] = pack2(ss[0]*ic, ss[1]*ic);
    *(unsigned int*)&T2[(size_t)node*64 + subl*2] =
        pack2(fmaf(wss, bflo(uhn), tt[0])*rd, fmaf(wss, bfhi(uhn), tt[1])*rd);
  }
}

// ---------------- MFMA bf16 matmul with fused epilogues (B pre-packed bf16) ----------------
// ep: 0 = plain bf16 store; 1 = BN+relu; 2 = ELU; 3 = sage (+bias, row L2-norm, relu);
//     4 = plain store + row-dot with p1/p2 -> y1/y2 (attention fold)
struct MME {
  const unsigned short* A; const unsigned short* Wb;   // Wb: bf16 [64][K] (= W^T)
  const unsigned short* A2; const unsigned short* Wb2; // optional second segment (K2=64)
  unsigned short* C;
  const float* b; const float* p1; const float* p2;
  float* y1; float* y2;
  int lda, ldc, col0, K, ep;
};
struct MMP { MME e[6]; int N; };

__global__ __launch_bounds__(256) void k_mm_mfma(MMP p){
  MME m = p.e[blockIdx.y];
  const int N = p.N;
  int tid = threadIdx.x;
  int w = tid >> 6, lane = tid & 63, quad = lane >> 4, m16 = lane & 15;
  int rowa = blockIdx.x*64 + w*16 + m16;
  int rowc = rowa < N ? rowa : N - 1;
  const int K = m.K;
  f32x4 acc[4];
  #pragma unroll
  for(int t = 0; t < 4; t++){ acc[t][0]=0.f; acc[t][1]=0.f; acc[t][2]=0.f; acc[t][3]=0.f; }
  for(int kc = 0; kc < K; kc += 64){
    bf16x8 a0 = *(const bf16x8*)&m.A[(size_t)rowc*m.lda + kc + quad*8];
    bf16x8 a1 = *(const bf16x8*)&m.A[(size_t)rowc*m.lda + kc + 32 + quad*8];
    #pragma unroll
    for(int t = 0; t < 4; t++){
      bf16x8 b0 = *(const bf16x8*)&m.Wb[(size_t)(t*16 + m16)*K + kc + quad*8];
      bf16x8 b1 = *(const bf16x8*)&m.Wb[(size_t)(t*16 + m16)*K + kc + 32 + quad*8];
      acc[t] = __builtin_amdgcn_mfma_f32_16x16x32_bf16(a0, b0, acc[t], 0, 0, 0);
      acc[t] = __builtin_amdgcn_mfma_f32_16x16x32_bf16(a1, b1, acc[t], 0, 0, 0);
    }
  }
  if(m.A2){
    bf16x8 a0 = *(const bf16x8*)&m.A2[(size_t)rowc*64 + quad*8];
    bf16x8 a1 = *(const bf16x8*)&m.A2[(size_t)rowc*64 + 32 + quad*8];
    #pragma unroll
    for(int t = 0; t < 4; t++){
      bf16x8 b0 = *(const bf16x8*)&m.Wb2[(size_t)(t*16 + m16)*64 + quad*8];
      bf16x8 b1 = *(const bf16x8*)&m.Wb2[(size_t)(t*16 + m16)*64 + 32 + quad*8];
      acc[t] = __builtin_amdgcn_mfma_f32_16x16x32_bf16(a0, b0, acc[t], 0, 0, 0);
      acc[t] = __builtin_amdgcn_mfma_f32_16x16x32_bf16(a1, b1, acc[t], 0, 0, 0);
    }
  }
  int robase = blockIdx.x*64 + w*16 + quad*4;
  if(m.ep == 3){
    // sage: v = acc + b, row L2-norm (cols live on 16 lanes of this quad x 4 regs), relu
    float v[4][4], n2[4] = {0,0,0,0};
    #pragma unroll
    for(int t = 0; t < 4; t++){
      float bv = m.b[m.col0 + t*16 + m16];
      #pragma unroll
      for(int r = 0; r < 4; r++){ v[t][r] = acc[t][r] + bv; n2[r] = fmaf(v[t][r], v[t][r], n2[r]); }
    }
    #pragma unroll
    for(int d = 8; d >= 1; d >>= 1){
      #pragma unroll
      for(int r = 0; r < 4; r++) n2[r] += __shfl_xor(n2[r], d, 64);
    }
    float inv[4];
    #pragma unroll
    for(int r = 0; r < 4; r++) inv[r] = 1.0f / fmaxf(sqrtf(n2[r]), 1e-12f);
    #pragma unroll
    for(int t = 0; t < 4; t++){
      #pragma unroll
      for(int r = 0; r < 4; r++){
        int ro = robase + r;
        if(ro < N) m.C[(size_t)ro*m.ldc + m.col0 + t*16 + m16] = f2bf(fmaxf(v[t][r]*inv[r], 0.f));
      }
    }
    return;
  }
  #pragma unroll
  for(int t = 0; t < 4; t++){
    int col = m.col0 + t*16 + m16;
    float bv = (m.ep == 1 || m.ep == 2) ? m.b[col] : 0.f;
    float gm = (m.ep == 1) ? m.p1[col]*rsqrtf(1.0f + 1e-5f) : 0.f;
    float be = (m.ep == 1) ? m.p2[col] : 0.f;
    #pragma unroll
    for(int r = 0; r < 4; r++){
      int ro = robase + r;
      if(ro < N){
        float val = acc[t][r];
        if(m.ep == 1)      val = fmaxf((val + bv)*gm + be, 0.f);
        else if(m.ep == 2) val = elu1(val + bv);
        m.C[(size_t)ro*m.ldc + col + 0] = f2bf(val);
      }
    }
  }
  if(m.ep == 4){
    float ps[4] = {0,0,0,0}, pd[4] = {0,0,0,0};
    #pragma unroll
    for(int t = 0; t < 4; t++){
      int col = m.col0 + t*16 + m16;
      float a_ = m.p1[col], d_ = m.p2[col];
      #pragma unroll
      for(int r = 0; r < 4; r++){ ps[r] = fmaf(acc[t][r], a_, ps[r]); pd[r] = fmaf(acc[t][r], d_, pd[r]); }
    }
    #pragma unroll
    for(int d = 8; d >= 1; d >>= 1){
      #pragma unroll
      for(int r = 0; r < 4; r++){ ps[r] += __shfl_xor(ps[r], d, 64); pd[r] += __shfl_xor(pd[r], d, 64); }
    }
    if(m16 == 0){
      #pragma unroll
      for(int r = 0; r < 4; r++){
        int ro = robase + r;
        if(ro < N){ m.y1[ro] = ps[r]; m.y2[ro] = pd[r]; }
      }
    }
  }
}

// ---------------- final: GCN2 mm + SAGE2 dual mm + L2norm + GAT2 add + gate combine ----------------
__global__ __launch_bounds__(256) void k_mm_final(
    const unsigned short* __restrict__ A2agg, const unsigned short* __restrict__ wb_gcn2,
    const float* __restrict__ gcn_b2,
    const unsigned short* __restrict__ S2agg, const unsigned short* __restrict__ wb_wl2,
    const float* __restrict__ bl2,
    const unsigned short* __restrict__ s1, const unsigned short* __restrict__ wb_wr2,
    const unsigned short* __restrict__ T2, const float* __restrict__ gat_b2,
    const float* __restrict__ gatew, float* __restrict__ out, int N){
  int tid = threadIdx.x;
  int w = tid >> 6, lane = tid & 63, quad = lane >> 4, m16 = lane & 15;
  int rowa = blockIdx.x*64 + w*16 + m16;
  int rowc = rowa < N ? rowa : N - 1;
  f32x4 accg[4], accs[4];
  #pragma unroll
  for(int t = 0; t < 4; t++){
    accg[t][0]=0.f; accg[t][1]=0.f; accg[t][2]=0.f; accg[t][3]=0.f;
    accs[t][0]=0.f; accs[t][1]=0.f; accs[t][2]=0.f; accs[t][3]=0.f;
  }
  // segment 1: A2agg @ gcn_w2
  {
    bf16x8 a0 = *(const bf16x8*)&A2agg[(size_t)rowc*64 + quad*8];
    bf16x8 a1 = *(const bf16x8*)&A2agg[(size_t)rowc*64 + 32 + quad*8];
    #pragma unroll
    for(int t = 0; t < 4; t++){
      bf16x8 b0 = *(const bf16x8*)&wb_gcn2[(size_t)(t*16 + m16)*64 + quad*8];
      bf16x8 b1 = *(const bf16x8*)&wb_gcn2[(size_t)(t*16 + m16)*64 + 32 + quad*8];
      accg[t] = __builtin_amdgcn_mfma_f32_16x16x32_bf16(a0, b0, accg[t], 0, 0, 0);
      accg[t] = __builtin_amdgcn_mfma_f32_16x16x32_bf16(a1, b1, accg[t], 0, 0, 0);
    }
  }
  // segment 2: S2agg @ wl2
  {
    bf16x8 a0 = *(const bf16x8*)&S2agg[(size_t)rowc*64 + quad*8];
    bf16x8 a1 = *(const bf16x8*)&S2agg[(size_t)rowc*64 + 32 + quad*8];
    #pragma unroll
    for(int t = 0; t < 4; t++){
      bf16x8 b0 = *(const bf16x8*)&wb_wl2[(size_t)(t*16 + m16)*64 + quad*8];
      bf16x8 b1 = *(const bf16x8*)&wb_wl2[(size_t)(t*16 + m16)*64 + 32 + quad*8];
      accs[t] = __builtin_amdgcn_mfma_f32_16x16x32_bf16(a0, b0, accs[t], 0, 0, 0);
      accs[t] = __builtin_amdgcn_mfma_f32_16x16x32_bf16(a1, b1, accs[t], 0, 0, 0);
    }
  }
  // segment 3: s1 @ wr2
  {
    bf16x8 a0 = *(const bf16x8*)&s1[(size_t)rowc*64 + quad*8];
    bf16x8 a1 = *(const bf16x8*)&s1[(size_t)rowc*64 + 32 + quad*8];
    #pragma unroll
    for(int t = 0; t < 4; t++){
      bf16x8 b0 = *(const bf16x8*)&wb_wr2[(size_t)(t*16 + m16)*64 + quad*8];
      bf16x8 b1 = *(const bf16x8*)&wb_wr2[(size_t)(t*16 + m16)*64 + 32 + quad*8];
      accs[t] = __builtin_amdgcn_mfma_f32_16x16x32_bf16(a0, b0, accs[t], 0, 0, 0);
      accs[t] = __builtin_amdgcn_mfma_f32_16x16x32_bf16(a1, b1, accs[t], 0, 0, 0);
    }
  }
  // epilogue
  float w0 = gatew[0], w1 = gatew[1], w2 = gatew[2];
  int robase = blockIdx.x*64 + w*16 + quad*4;
  float vs[4][4], n2[4] = {0,0,0,0};
  #pragma unroll
  for(int t = 0; t < 4; t++){
    float bsv = bl2[t*16 + m16];
    #pragma unroll
    for(int r = 0; r < 4; r++){ vs[t][r] = accs[t][r] + bsv; n2[r] = fmaf(vs[t][r], vs[t][r], n2[r]); }
  }
  #pragma unroll
  for(int d = 8; d >= 1; d >>= 1){
    #pragma unroll
    for(int r = 0; r < 4; r++) n2[r] += __shfl_xor(n2[r], d, 64);
  }
  float inv[4];
  #pragma unroll
  for(int r = 0; r < 4; r++) inv[r] = 1.0f / fmaxf(sqrtf(n2[r]), 1e-12f);
  #pragma unroll
  for(int t = 0; t < 4; t++){
    int col = t*16 + m16;
    float bg = gcn_b2[col], bt = gat_b2[col];
    #pragma unroll
    for(int r = 0; r < 4; r++){
      int ro = robase + r;
      if(ro < N){
        float t2 = bflo((unsigned int)T2[(size_t)ro*64 + col]);
        out[(size_t)ro*64 + col] = w0*(accg[t][r] + bg) + w1*(t2 + bt) + w2*vs[t][r]*inv[r];
      }
    }
  }
}

// ---------------- host ----------------
extern "C" void kernel_launch(void* const* d_in, const int* in_sizes, int n_in,
                              void* d_out, int out_size, void* d_ws, size_t ws_size,
                              hipStream_t stream){
  const float* x        = (const float*)d_in[0];
  const int*   ei       = (const int*)d_in[1];
  const int*   row      = ei;
  const int*   col      = ei + NE;
  const float* gate_w1  = (const float*)d_in[2];
  const float* gate_b1  = (const float*)d_in[3];
  const float* gate_w2  = (const float*)d_in[4];
  const float* gate_b2  = (const float*)d_in[5];
  const float* gcn_w1   = (const float*)d_in[6];
  const float* gcn_b1   = (const float*)d_in[7];
  const float* bn_gamma = (const float*)d_in[8];
  const float* bn_beta  = (const float*)d_in[9];
  const float* gcn_w2   = (const float*)d_in[10];
  const float* gcn_b2   = (const float*)d_in[11];
  const float* gat_w1   = (const float*)d_in[12];
  const float* gat_as1  = (const float*)d_in[13];
  const float* gat_ad1  = (const float*)d_in[14];
  const float* gat_b1   = (const float*)d_in[15];
  const float* gat_w2   = (const float*)d_in[16];
  const float* gat_as2  = (const float*)d_in[17];
  const float* gat_ad2  = (const float*)d_in[18];
  const float* gat_b2   = (const float*)d_in[19];
  const float* sage_wl1 = (const float*)d_in[20];
  const float* sage_bl1 = (const float*)d_in[21];
  const float* sage_wr1 = (const float*)d_in[22];
  const float* sage_wl2 = (const float*)d_in[23];
  const float* sage_bl2 = (const float*)d_in[24];
  const float* sage_wr2 = (const float*)d_in[25];
  float* out = (float*)d_out;

  char* wp = (char*)d_ws;
  auto alloc = [&](size_t bytes)->char*{ char* p = wp; wp += (bytes + 255) & ~(size_t)255; return p; };
  // zero-init region (contiguous): cnt, cursor, gsum, total
  int*   cnt    = (int*)  alloc((size_t)NN*4);
  int*   cursor = (int*)  alloc((size_t)NN*4);
  float* gsum   = (float*)alloc(64*4);
  int*   total  = (int*)  alloc(256);
  size_t zbytes = (size_t)(wp - (char*)cnt);
  int*   offs   = (int*)  alloc((size_t)NN*4);
  int*   csr    = (int*)  alloc((size_t)NE*4);
  float* dis    = (float*)alloc((size_t)NN*4);
  float* invc   = (float*)alloc((size_t)NN*4);
  float* gatew  = (float*)alloc(16);
  float* wsd    = (float*)alloc(64*8*4);
  float* asrc1  = (float*)alloc((size_t)NN*4*4);
  float* adst1  = (float*)alloc((size_t)NN*4*4);
  float* asrc2  = (float*)alloc((size_t)NN*4);
  float* adst2  = (float*)alloc((size_t)NN*4);
  float* wvE1   = (float*)alloc((size_t)NE*4*4);
  float* rden1  = (float*)alloc((size_t)NN*4*4);
  float* wvS1   = (float*)alloc((size_t)NN*4*4);
  float* wvE2   = (float*)alloc((size_t)NE*4);
  float* rden2  = (float*)alloc((size_t)NN*4);
  float* wvS2   = (float*)alloc((size_t)NN*4);
  unsigned short* xb     = (unsigned short*)alloc((size_t)NN*64*2);
  unsigned short* z      = (unsigned short*)alloc((size_t)NN*256*2);
  unsigned short* agcnx  = (unsigned short*)alloc((size_t)NN*64*2);
  unsigned short* asagex = (unsigned short*)alloc((size_t)NN*64*2);
  unsigned short* a1     = (unsigned short*)alloc((size_t)NN*64*2);
  unsigned short* s1     = (unsigned short*)alloc((size_t)NN*64*2);
  unsigned short* gath   = (unsigned short*)alloc((size_t)NN*256*2);
  unsigned short* h2     = (unsigned short*)alloc((size_t)NN*64*2);
  unsigned short* A2agg  = (unsigned short*)alloc((size_t)NN*64*2);
  unsigned short* S2agg  = (unsigned short*)alloc((size_t)NN*64*2);
  unsigned short* T2     = (unsigned short*)alloc((size_t)NN*64*2);
  // packed bf16 weights (B-operand layout [n][K])
  unsigned short* wb_gcn1 = (unsigned short*)alloc((size_t)64*64*2);
  unsigned short* wb_wl1  = (unsigned short*)alloc((size_t)64*64*2);
  unsigned short* wb_wr1  = (unsigned short*)alloc((size_t)64*64*2);
  unsigned short* wb_gat1 = (unsigned short*)alloc((size_t)256*64*2);
  unsigned short* wb_gat2 = (unsigned short*)alloc((size_t)64*256*2);
  unsigned short* wb_gcn2 = (unsigned short*)alloc((size_t)64*64*2);
  unsigned short* wb_wl2  = (unsigned short*)alloc((size_t)64*64*2);
  unsigned short* wb_wr2  = (unsigned short*)alloc((size_t)64*64*2);

  hipMemsetAsync(cnt, 0, zbytes, stream);

  const int gN  = (NN + 63) / 64;   // 782
  const int g4  = NN / 4;           // 12500
  const int g16 = NN / 16;          // 3125
  const int gA  = (NN + 255) / 256; // 196

  // pack weights (independent of graph work; serialized on stream anyway)
  {
    PKP pk = {};
    pk.s[0]  = {gcn_w1,   wb_gcn1,            6, 64,  0};
    pk.s[1]  = {sage_wl1, wb_wl1,             6, 64,  0};
    pk.s[2]  = {sage_wr1, wb_wr1,             6, 64,  0};
    pk.s[3]  = {gat_w1,   wb_gat1 + 0*64*64,  6, 256, 0};
    pk.s[4]  = {gat_w1,   wb_gat1 + 1*64*64,  6, 256, 64};
    pk.s[5]  = {gat_w1,   wb_gat1 + 2*64*64,  6, 256, 128};
    pk.s[6]  = {gat_w1,   wb_gat1 + 3*64*64,  6, 256, 192};
    pk.s[7]  = {gat_w2,   wb_gat2,            8, 64,  0};
    pk.s[8]  = {gcn_w2,   wb_gcn2,            6, 64,  0};
    pk.s[9]  = {sage_wl2, wb_wl2,             6, 64,  0};
    pk.s[10] = {sage_wr2, wb_wr2,             6, 64,  0};
    k_packw<<<11, 256, 0, stream>>>(pk);
  }

  k_count<<<(NE+255)/256, 256, 0, stream>>>(col, cnt, NE);
  k_alloc<<<gA, 256, 0, stream>>>(cnt, offs, dis, invc, total, NN);
  k_fill <<<(NE+255)/256, 256, 0, stream>>>(row, col, offs, cursor, csr, NE);
  k_castsum<<<256, 256, 0, stream>>>(x, xb, gsum, NN);
  k_gate  <<<1, 64, 0, stream>>>(gsum, gate_w1, gate_b1, gate_w2, gate_b2, gatew);
  k_fold1 <<<1, 256, 0, stream>>>(gat_w1, gat_as1, gat_ad1, wsd);
  k_attdotx<<<g16, 256, 0, stream>>>(xb, wsd, asrc1, adst1, NN);
  k_edgew1<<<g4, 256, 0, stream>>>(asrc1, adst1, offs, cnt, csr, wvE1, rden1, wvS1, NN);

  // ---- layer-1 one-pass pre-aggregation over xb ----
  k_aggx<<<g4, 256, 0, stream>>>(xb, wvE1, rden1, wvS1, dis, invc, offs, cnt, csr,
                                 z, agcnx, asagex, NN);

  // ---- layer-1 matmuls with fused activations (6 entries, one dispatch) ----
  {
    MMP p = {};
    p.N = NN;
    p.e[0] = {agcnx, wb_gcn1, nullptr, nullptr, a1, gcn_b1, bn_gamma, bn_beta,
              nullptr, nullptr, 64, 64, 0, 64, 1};
    p.e[1] = {asagex, wb_wl1, xb, wb_wr1, s1, sage_bl1, nullptr, nullptr,
              nullptr, nullptr, 64, 64, 0, 64, 3};
    for(int hd = 0; hd < 4; hd++)
      p.e[2+hd] = {z + hd*64, wb_gat1 + (size_t)hd*64*64, nullptr, nullptr, gath, gat_b1,
                   nullptr, nullptr, nullptr, nullptr, 256, 256, hd*64, 64, 2};
    k_mm_mfma<<<dim3(gN,6), 256, 0, stream>>>(p);
  }

  // ---- GAT layer 2 matmul (K=256) + folded attention dots ----
  {
    MMP p = {};
    p.N = NN;
    p.e[0] = {gath, wb_gat2, nullptr, nullptr, h2, nullptr, gat_as2, gat_ad2,
              asrc2, adst2, 256, 64, 0, 256, 4};
    k_mm_mfma<<<dim3(gN,1), 256, 0, stream>>>(p);
  }
  k_edgew2<<<g4, 256, 0, stream>>>(asrc2, adst2, offs, cnt, csr, wvE2, rden2, wvS2, NN);

  // ---- layer-2 one-pass pre-aggregation ----
  k_aggf<<<g4, 256, 0, stream>>>(a1, s1, h2, wvE2, rden2, wvS2, dis, invc,
                                 offs, cnt, csr, A2agg, S2agg, T2, NN);

  // ---- final matmuls + gate combine ----
  k_mm_final<<<gN, 256, 0, stream>>>(A2agg, wb_gcn2, gcn_b2, S2agg, wb_wl2, sage_bl2,
                                     s1, wb_wr2, T2, gat_b2, gatew, out, NN);
}

// Round 2
// 372.933 us; speedup vs baseline: 1.0690x; 1.0690x over previous
//
#include <hip/hip_runtime.h>
#include <hip/hip_bf16.h>
#include <math.h>

#define NN 50000
#define NE 400000

typedef __attribute__((ext_vector_type(8))) short bf16x8;
typedef __attribute__((ext_vector_type(4))) float f32x4;

// ---------------- helpers ----------------
__device__ __forceinline__ float lrelu(float v){ return v > 0.f ? v : 0.2f*v; }
__device__ __forceinline__ float elu1(float v){ return v > 0.f ? v : expm1f(v); }
__device__ __forceinline__ float bflo(unsigned int u){ return __uint_as_float(u << 16); }
__device__ __forceinline__ float bfhi(unsigned int u){ return __uint_as_float(u & 0xffff0000u); }
__device__ __forceinline__ unsigned short f2bf(float f){
  __hip_bfloat16 h = __float2bfloat16(f);
  return *(unsigned short*)&h;
}
__device__ __forceinline__ unsigned int pack2(float lo, float hi){
  return (unsigned int)f2bf(lo) | ((unsigned int)f2bf(hi) << 16);
}

// stage a packed bf16 [64][64] table into LDS with pitch 72 (2-way-free reads)
__device__ __forceinline__ void stage_tab(unsigned short* Wt, const unsigned short* Wb, int tid){
  #pragma unroll
  for(int s = 0; s < 2; s++){
    int c = tid + s*256;           // 512 chunks of 8 elems
    int n = c >> 3, ko = (c & 7)*8;
    *(bf16x8*)&Wt[n*72 + ko] = *(const bf16x8*)&Wb[n*64 + ko];
  }
}

// ---------------- CSR build ----------------
__global__ void k_count(const int* __restrict__ col, int* __restrict__ cnt, int E){
  int e = blockIdx.x*blockDim.x + threadIdx.x;
  if(e < E) atomicAdd(&cnt[col[e]], 1);
}

__global__ void k_alloc(const int* __restrict__ cnt, int* __restrict__ offs,
                        float* __restrict__ dis, float* __restrict__ invc,
                        int* __restrict__ total, int N){
  int i = blockIdx.x*blockDim.x + threadIdx.x;
  int lane = threadIdx.x & 63;
  int v = (i < N) ? cnt[i] : 0;
  int x = v;
  #pragma unroll
  for(int d = 1; d < 64; d <<= 1){ int t = __shfl_up(x, d, 64); if(lane >= d) x += t; }
  int base = 0;
  if(lane == 63 && x > 0) base = atomicAdd(total, x);
  base = __shfl(base, 63, 64);
  if(i < N){
    offs[i] = base + x - v;
    dis[i]  = 1.0f / sqrtf((float)(v + 1));
    invc[i] = 1.0f / fmaxf((float)v, 1.0f);
  }
}

__global__ void k_fill(const int* __restrict__ row, const int* __restrict__ col,
                       const int* __restrict__ offs, int* __restrict__ cursor,
                       int* __restrict__ csr, int E){
  int e = blockIdx.x*blockDim.x + threadIdx.x;
  if(e < E){
    int c = col[e];
    int pos = offs[c] + atomicAdd(&cursor[c], 1);
    csr[pos] = row[e];
  }
}

// ---------------- pack weights to bf16, B-fragment layout [n][k] ----------------
struct PKS { const float* src; unsigned short* dst; int kshift; int ldw; int col0; };
struct PKP { PKS s[11]; };

__global__ void k_packw(PKP p){
  PKS s = p.s[blockIdx.x];
  int K = 1 << s.kshift;
  int total = K << 6;            // 64 output columns (n) x K
  for(int idx = threadIdx.x; idx < total; idx += 256){
    int n = idx >> s.kshift, k = idx & (K - 1);
    s.dst[idx] = f2bf(s.src[(size_t)k*s.ldw + s.col0 + n]);
  }
}

// ---------------- cast x -> bf16 + column sums for gate ----------------
__global__ void k_castsum(const float* __restrict__ x, unsigned short* __restrict__ xb,
                          float* __restrict__ gsum, int N){
  __shared__ float part[4][64];
  int lane = threadIdx.x & 63, w = threadIdx.x >> 6;
  float s = 0.f;
  for(int r = blockIdx.x*4 + w; r < N; r += gridDim.x*4){
    float v = x[(size_t)r*64 + lane];
    xb[(size_t)r*64 + lane] = f2bf(v);
    s += v;
  }
  part[w][lane] = s;
  __syncthreads();
  if(w == 0) atomicAdd(&gsum[lane], part[0][lane]+part[1][lane]+part[2][lane]+part[3][lane]);
}

__global__ void k_gate(const float* __restrict__ gsum,
                       const float* __restrict__ w1, const float* __restrict__ b1,
                       const float* __restrict__ w2, const float* __restrict__ b2,
                       float* __restrict__ gatew){
  __shared__ float g[64]; __shared__ float hid[64]; __shared__ float lg[3];
  int t = threadIdx.x;
  g[t] = gsum[t] * (1.0f/(float)NN);
  __syncthreads();
  float acc = b1[t];
  for(int i = 0; i < 64; i++) acc += g[i]*w1[i*64 + t];
  hid[t] = fmaxf(acc, 0.f);
  __syncthreads();
  if(t < 3){
    float a = b2[t];
    for(int j = 0; j < 64; j++) a += hid[j]*w2[j*3 + t];
    lg[t] = a;
  }
  __syncthreads();
  if(t == 0){
    float m = fmaxf(lg[0], fmaxf(lg[1], lg[2]));
    float e0 = expf(lg[0]-m), e1 = expf(lg[1]-m), e2 = expf(lg[2]-m);
    float s = e0 + e1 + e2;
    gatew[0] = e0/s; gatew[1] = e1/s; gatew[2] = e2/s;
  }
}

// ---------------- fold GAT1 attention vectors through W ----------------
__global__ void k_fold1(const float* __restrict__ w1, const float* __restrict__ as,
                        const float* __restrict__ ad, float* __restrict__ wsd){
  int t = threadIdx.x;            // 256
  int k = t & 63, h = t >> 6;
  float ssrc = 0.f, sdst = 0.f;
  for(int c = 0; c < 64; c++){
    float w = w1[k*256 + h*64 + c];
    ssrc += w * as[h*64 + c];
    sdst += w * ad[h*64 + c];
  }
  wsd[k*8 + h] = ssrc;
  wsd[k*8 + 4 + h] = sdst;
}

// ---------------- asrc1/adst1 = xb @ Wsd  (16 lanes per node) ----------------
__global__ void k_attdotx(const unsigned short* __restrict__ xb, const float* __restrict__ wsd,
                          float* __restrict__ asrc, float* __restrict__ adst, int N){
  __shared__ float ws[64*8];
  int tid = threadIdx.x;
  ws[tid] = wsd[tid];
  ws[tid + 256] = wsd[tid + 256];
  __syncthreads();
  int node = blockIdx.x*16 + (tid >> 4);
  int l = tid & 15;
  if(node >= N) return;
  uint2 u = *(const uint2*)&xb[(size_t)node*64 + l*4];
  float v0 = bflo(u.x), v1 = bfhi(u.x), v2 = bflo(u.y), v3 = bfhi(u.y);
  float s[8];
  #pragma unroll
  for(int h = 0; h < 8; h++){
    s[h] = v0*ws[(l*4+0)*8+h] + v1*ws[(l*4+1)*8+h] + v2*ws[(l*4+2)*8+h] + v3*ws[(l*4+3)*8+h];
  }
  #pragma unroll
  for(int d = 8; d >= 1; d >>= 1){
    #pragma unroll
    for(int h = 0; h < 8; h++) s[h] += __shfl_xor(s[h], d, 16);
  }
  if(l == 0){
    float4 o1; o1.x = s[0]; o1.y = s[1]; o1.z = s[2]; o1.w = s[3];
    float4 o2; o2.x = s[4]; o2.y = s[5]; o2.z = s[6]; o2.w = s[7];
    *(float4*)&asrc[node*4] = o1;
    *(float4*)&adst[node*4] = o2;
  }
}

// ---------------- GAT edge weights ----------------
__global__ void k_edgew1(const float* __restrict__ asrc, const float* __restrict__ adst,
                         const int* __restrict__ offs, const int* __restrict__ cnt,
                         const int* __restrict__ csr,
                         float* __restrict__ wvE, float* __restrict__ rdenN,
                         float* __restrict__ wvS, int N){
  int node = blockIdx.x*4 + (threadIdx.x >> 6);
  int lane = threadIdx.x & 63;
  if(node >= N) return;
  float4 ad = *(const float4*)&adst[node*4];
  float a0 = 0.f, a1 = 0.f, a2 = 0.f, a3 = 0.f;
  int e0 = offs[node], e1 = e0 + cnt[node];
  for(int e = e0 + lane; e < e1; e += 64){
    int s = csr[e];
    float4 as = *(const float4*)&asrc[s*4];
    float4 w;
    w.x = expf(lrelu(as.x + ad.x));
    w.y = expf(lrelu(as.y + ad.y));
    w.z = expf(lrelu(as.z + ad.z));
    w.w = expf(lrelu(as.w + ad.w));
    a0 += w.x; a1 += w.y; a2 += w.z; a3 += w.w;
    *(float4*)&wvE[(size_t)e*4] = w;
  }
  #pragma unroll
  for(int d = 32; d >= 1; d >>= 1){
    a0 += __shfl_xor(a0, d, 64); a1 += __shfl_xor(a1, d, 64);
    a2 += __shfl_xor(a2, d, 64); a3 += __shfl_xor(a3, d, 64);
  }
  float4 asl = *(const float4*)&asrc[node*4];
  float4 ws;
  ws.x = expf(lrelu(asl.x + ad.x));
  ws.y = expf(lrelu(asl.y + ad.y));
  ws.z = expf(lrelu(asl.z + ad.z));
  ws.w = expf(lrelu(asl.w + ad.w));
  if(lane == 0){
    float4 rd;
    rd.x = 1.0f/(a0 + ws.x); rd.y = 1.0f/(a1 + ws.y);
    rd.z = 1.0f/(a2 + ws.z); rd.w = 1.0f/(a3 + ws.w);
    *(float4*)&rdenN[node*4] = rd;
    *(float4*)&wvS[node*4] = ws;
  }
}

__global__ void k_edgew2(const float* __restrict__ asrc, const float* __restrict__ adst,
                         const int* __restrict__ offs, const int* __restrict__ cnt,
                         const int* __restrict__ csr,
                         float* __restrict__ wvE, float* __restrict__ rdenN,
                         float* __restrict__ wvS, int N){
  int node = blockIdx.x*4 + (threadIdx.x >> 6);
  int lane = threadIdx.x & 63;
  if(node >= N) return;
  float ad = adst[node];
  float acc = 0.f;
  int e0 = offs[node], e1 = e0 + cnt[node];
  for(int e = e0 + lane; e < e1; e += 64){
    float w = expf(lrelu(asrc[csr[e]] + ad));
    acc += w;
    wvE[e] = w;
  }
  #pragma unroll
  for(int d = 32; d >= 1; d >>= 1) acc += __shfl_xor(acc, d, 64);
  float ws = expf(lrelu(asrc[node] + ad));
  if(lane == 0){
    rdenN[node] = 1.0f/(acc + ws);
    wvS[node] = ws;
  }
}

// ---------------- layer-1 one-pass pre-aggregation over xb ----------------
__global__ void k_aggx(const unsigned short* __restrict__ xb,
                       const float* __restrict__ wvE, const float* __restrict__ rden,
                       const float* __restrict__ wvS,
                       const float* __restrict__ dis, const float* __restrict__ invc,
                       const int* __restrict__ offs, const int* __restrict__ cnt,
                       const int* __restrict__ csr,
                       unsigned short* __restrict__ z, unsigned short* __restrict__ agcnx,
                       unsigned short* __restrict__ asagex, int N){
  int node = blockIdx.x*4 + (threadIdx.x >> 6);
  int lane = threadIdx.x & 63;
  if(node >= N) return;
  int half = lane >> 5, subl = lane & 31;      // subl*2, subl*2+1 channels
  float zg[4][2] = {{0,0},{0,0},{0,0},{0,0}};
  float gg[2] = {0,0}, ssv[2] = {0,0};
  int e0 = offs[node], e1 = e0 + cnt[node];
  #pragma unroll 2
  for(int e = e0 + half; e < e1; e += 2){
    int s = csr[e];
    float4 w4 = *(const float4*)&wvE[(size_t)e*4];
    float ds = dis[s];
    unsigned int u = *(const unsigned int*)&xb[(size_t)s*64 + subl*2];
    float xl = bflo(u), xh = bfhi(u);
    zg[0][0] = fmaf(w4.x, xl, zg[0][0]); zg[0][1] = fmaf(w4.x, xh, zg[0][1]);
    zg[1][0] = fmaf(w4.y, xl, zg[1][0]); zg[1][1] = fmaf(w4.y, xh, zg[1][1]);
    zg[2][0] = fmaf(w4.z, xl, zg[2][0]); zg[2][1] = fmaf(w4.z, xh, zg[2][1]);
    zg[3][0] = fmaf(w4.w, xl, zg[3][0]); zg[3][1] = fmaf(w4.w, xh, zg[3][1]);
    gg[0] = fmaf(ds, xl, gg[0]); gg[1] = fmaf(ds, xh, gg[1]);
    ssv[0] += xl; ssv[1] += xh;
  }
  #pragma unroll
  for(int h = 0; h < 4; h++){
    zg[h][0] += __shfl_xor(zg[h][0], 32, 64);
    zg[h][1] += __shfl_xor(zg[h][1], 32, 64);
  }
  gg[0] += __shfl_xor(gg[0], 32, 64); gg[1] += __shfl_xor(gg[1], 32, 64);
  ssv[0] += __shfl_xor(ssv[0], 32, 64); ssv[1] += __shfl_xor(ssv[1], 32, 64);
  if(half == 0){
    unsigned int un = *(const unsigned int*)&xb[(size_t)node*64 + subl*2];
    float xl = bflo(un), xh = bfhi(un);
    float4 ws4 = *(const float4*)&wvS[node*4];
    float4 rd4 = *(const float4*)&rden[node*4];
    unsigned int* zp = (unsigned int*)&z[(size_t)node*256 + subl*2];
    zp[0]   = pack2((zg[0][0] + ws4.x*xl)*rd4.x, (zg[0][1] + ws4.x*xh)*rd4.x);
    zp[32]  = pack2((zg[1][0] + ws4.y*xl)*rd4.y, (zg[1][1] + ws4.y*xh)*rd4.y);
    zp[64]  = pack2((zg[2][0] + ws4.z*xl)*rd4.z, (zg[2][1] + ws4.z*xh)*rd4.z);
    zp[96]  = pack2((zg[3][0] + ws4.w*xl)*rd4.w, (zg[3][1] + ws4.w*xh)*rd4.w);
    float dc = dis[node], ic = invc[node];
    *(unsigned int*)&agcnx[(size_t)node*64 + subl*2] =
        pack2(dc*fmaf(dc, xl, gg[0]), dc*fmaf(dc, xh, gg[1]));
    *(unsigned int*)&asagex[(size_t)node*64 + subl*2] = pack2(ssv[0]*ic, ssv[1]*ic);
  }
}

// ---------------- layer-2 one-pass pre-aggregation over a1 / s1 / h2 ----------------
__global__ void k_aggf(const unsigned short* __restrict__ a1, const unsigned short* __restrict__ s1,
                       const unsigned short* __restrict__ h2,
                       const float* __restrict__ wvE, const float* __restrict__ rden,
                       const float* __restrict__ wvS,
                       const float* __restrict__ dis, const float* __restrict__ invc,
                       const int* __restrict__ offs, const int* __restrict__ cnt,
                       const int* __restrict__ csr,
                       unsigned short* __restrict__ A2agg, unsigned short* __restrict__ S2agg,
                       unsigned short* __restrict__ T2, int N){
  int node = blockIdx.x*4 + (threadIdx.x >> 6);
  int lane = threadIdx.x & 63;
  if(node >= N) return;
  int half = lane >> 5, subl = lane & 31;
  float aa[2] = {0,0}, ss[2] = {0,0}, tt[2] = {0,0};
  int e0 = offs[node], e1 = e0 + cnt[node];
  #pragma unroll 2
  for(int e = e0 + half; e < e1; e += 2){
    int s = csr[e];
    float ds = dis[s];
    float wv = wvE[e];
    unsigned int ua = *(const unsigned int*)&a1[(size_t)s*64 + subl*2];
    unsigned int us = *(const unsigned int*)&s1[(size_t)s*64 + subl*2];
    unsigned int uh = *(const unsigned int*)&h2[(size_t)s*64 + subl*2];
    aa[0] = fmaf(ds, bflo(ua), aa[0]); aa[1] = fmaf(ds, bfhi(ua), aa[1]);
    ss[0] += bflo(us); ss[1] += bfhi(us);
    tt[0] = fmaf(wv, bflo(uh), tt[0]); tt[1] = fmaf(wv, bfhi(uh), tt[1]);
  }
  aa[0] += __shfl_xor(aa[0], 32, 64); aa[1] += __shfl_xor(aa[1], 32, 64);
  ss[0] += __shfl_xor(ss[0], 32, 64); ss[1] += __shfl_xor(ss[1], 32, 64);
  tt[0] += __shfl_xor(tt[0], 32, 64); tt[1] += __shfl_xor(tt[1], 32, 64);
  if(half == 0){
    unsigned int uan = *(const unsigned int*)&a1[(size_t)node*64 + subl*2];
    unsigned int uhn = *(const unsigned int*)&h2[(size_t)node*64 + subl*2];
    float dc = dis[node], ic = invc[node];
    float rd = rden[node], wss = wvS[node];
    *(unsigned int*)&A2agg[(size_t)node*64 + subl*2] =
        pack2(dc*fmaf(dc, bflo(uan), aa[0]), dc*fmaf(dc, bfhi(uan), aa[1]));
    *(unsigned int*)&S2agg[(size_t)node*64 + subl*2] = pack2(ss[0]*ic, ss[1]*ic);
    *(unsigned int*)&T2[(size_t)node*64 + subl*2] =
        pack2(fmaf(wss, bflo(uhn), tt[0])*rd, fmaf(wss, bfhi(uhn), tt[1])*rd);
  }
}

// ---------------- fused GAT layer1+layer2 per 64-row block ----------------
// phase A: for h in 0..3: gathh = ELU(z[:,h*64:+64] @ W1h + b1h) -> LDS GH[64][264]
// phase B: h2 = GH @ W2 (K=256), + attention row-dots asrc2/adst2
__global__ __launch_bounds__(256) void k_gat12(
    const unsigned short* __restrict__ z, const unsigned short* __restrict__ wb1,
    const float* __restrict__ b1,
    const unsigned short* __restrict__ wb2,
    const float* __restrict__ as2, const float* __restrict__ ad2,
    unsigned short* __restrict__ h2, float* __restrict__ asrc2,
    float* __restrict__ adst2, int N){
  __shared__ unsigned short WT[64*72];     // per-head W1 (reused)
  __shared__ unsigned short GH[64*264];    // gath block, pitch 264
  int tid = threadIdx.x;
  int w = tid >> 6, lane = tid & 63, quad = lane >> 4, m16 = lane & 15;
  int rowa = blockIdx.x*64 + w*16 + m16;
  int rowc = rowa < N ? rowa : N - 1;
  int lr = w*16;                           // block-local stripe base
  for(int h = 0; h < 4; h++){
    stage_tab(WT, wb1 + (size_t)h*4096, tid);
    __syncthreads();
    bf16x8 a0 = *(const bf16x8*)&z[(size_t)rowc*256 + h*64 + quad*8];
    bf16x8 a1 = *(const bf16x8*)&z[(size_t)rowc*256 + h*64 + 32 + quad*8];
    f32x4 acc[4];
    #pragma unroll
    for(int t = 0; t < 4; t++){ acc[t][0]=0.f; acc[t][1]=0.f; acc[t][2]=0.f; acc[t][3]=0.f; }
    #pragma unroll
    for(int t = 0; t < 4; t++){
      bf16x8 b0 = *(const bf16x8*)&WT[(t*16 + m16)*72 + quad*8];
      bf16x8 b1v = *(const bf16x8*)&WT[(t*16 + m16)*72 + 32 + quad*8];
      acc[t] = __builtin_amdgcn_mfma_f32_16x16x32_bf16(a0, b0, acc[t], 0, 0, 0);
      acc[t] = __builtin_amdgcn_mfma_f32_16x16x32_bf16(a1, b1v, acc[t], 0, 0, 0);
    }
    #pragma unroll
    for(int t = 0; t < 4; t++){
      float bv = b1[h*64 + t*16 + m16];
      #pragma unroll
      for(int r = 0; r < 4; r++){
        GH[(lr + quad*4 + r)*264 + h*64 + t*16 + m16] = f2bf(elu1(acc[t][r] + bv));
      }
    }
    __syncthreads();
  }
  // phase B: GH (64x256) @ W2 (256x64)
  f32x4 acc2[4];
  #pragma unroll
  for(int t = 0; t < 4; t++){ acc2[t][0]=0.f; acc2[t][1]=0.f; acc2[t][2]=0.f; acc2[t][3]=0.f; }
  for(int kc = 0; kc < 256; kc += 64){
    bf16x8 a0 = *(const bf16x8*)&GH[(lr + m16)*264 + kc + quad*8];
    bf16x8 a1 = *(const bf16x8*)&GH[(lr + m16)*264 + kc + 32 + quad*8];
    #pragma unroll
    for(int t = 0; t < 4; t++){
      bf16x8 b0 = *(const bf16x8*)&wb2[(size_t)(t*16 + m16)*256 + kc + quad*8];
      bf16x8 b1v = *(const bf16x8*)&wb2[(size_t)(t*16 + m16)*256 + kc + 32 + quad*8];
      acc2[t] = __builtin_amdgcn_mfma_f32_16x16x32_bf16(a0, b0, acc2[t], 0, 0, 0);
      acc2[t] = __builtin_amdgcn_mfma_f32_16x16x32_bf16(a1, b1v, acc2[t], 0, 0, 0);
    }
  }
  // epilogue: store h2 (bf16) + attention dots
  int robase = blockIdx.x*64 + w*16 + quad*4;
  #pragma unroll
  for(int t = 0; t < 4; t++){
    int col = t*16 + m16;
    #pragma unroll
    for(int r = 0; r < 4; r++){
      int ro = robase + r;
      if(ro < N) h2[(size_t)ro*64 + col] = f2bf(acc2[t][r]);
    }
  }
  float ps[4] = {0,0,0,0}, pd[4] = {0,0,0,0};
  #pragma unroll
  for(int t = 0; t < 4; t++){
    int col = t*16 + m16;
    float a_ = as2[col], d_ = ad2[col];
    #pragma unroll
    for(int r = 0; r < 4; r++){ ps[r] = fmaf(acc2[t][r], a_, ps[r]); pd[r] = fmaf(acc2[t][r], d_, pd[r]); }
  }
  #pragma unroll
  for(int d = 8; d >= 1; d >>= 1){
    #pragma unroll
    for(int r = 0; r < 4; r++){ ps[r] += __shfl_xor(ps[r], d, 64); pd[r] += __shfl_xor(pd[r], d, 64); }
  }
  if(m16 == 0){
    #pragma unroll
    for(int r = 0; r < 4; r++){
      int ro = robase + r;
      if(ro < N){ asrc2[ro] = ps[r]; adst2[ro] = pd[r]; }
    }
  }
}

// ---------------- MFMA bf16 matmul (K=64, B staged in LDS from packed bf16) ----------------
// ep: 1 = BN+relu; 3 = sage (+bias, row L2-norm, relu)
struct MME {
  const unsigned short* A; const unsigned short* Wb;
  const unsigned short* A2; const unsigned short* Wb2;  // optional second segment (K2=64)
  unsigned short* C;
  const float* b; const float* p1; const float* p2;
  int ep;
};
struct MMP { MME e[2]; int N; };

__global__ __launch_bounds__(256) void k_mm_mfma(MMP p){
  __shared__ unsigned short Wt[64*72];
  __shared__ unsigned short Wt2[64*72];
  MME m = p.e[blockIdx.y];
  const int N = p.N;
  int tid = threadIdx.x;
  stage_tab(Wt, m.Wb, tid);
  if(m.Wb2) stage_tab(Wt2, m.Wb2, tid);
  __syncthreads();
  int w = tid >> 6, lane = tid & 63, quad = lane >> 4, m16 = lane & 15;
  int rowa = blockIdx.x*64 + w*16 + m16;
  int rowc = rowa < N ? rowa : N - 1;
  f32x4 acc[4];
  #pragma unroll
  for(int t = 0; t < 4; t++){ acc[t][0]=0.f; acc[t][1]=0.f; acc[t][2]=0.f; acc[t][3]=0.f; }
  {
    bf16x8 a0 = *(const bf16x8*)&m.A[(size_t)rowc*64 + quad*8];
    bf16x8 a1 = *(const bf16x8*)&m.A[(size_t)rowc*64 + 32 + quad*8];
    #pragma unroll
    for(int t = 0; t < 4; t++){
      bf16x8 b0 = *(const bf16x8*)&Wt[(t*16 + m16)*72 + quad*8];
      bf16x8 b1 = *(const bf16x8*)&Wt[(t*16 + m16)*72 + 32 + quad*8];
      acc[t] = __builtin_amdgcn_mfma_f32_16x16x32_bf16(a0, b0, acc[t], 0, 0, 0);
      acc[t] = __builtin_amdgcn_mfma_f32_16x16x32_bf16(a1, b1, acc[t], 0, 0, 0);
    }
  }
  if(m.A2){
    bf16x8 a0 = *(const bf16x8*)&m.A2[(size_t)rowc*64 + quad*8];
    bf16x8 a1 = *(const bf16x8*)&m.A2[(size_t)rowc*64 + 32 + quad*8];
    #pragma unroll
    for(int t = 0; t < 4; t++){
      bf16x8 b0 = *(const bf16x8*)&Wt2[(t*16 + m16)*72 + quad*8];
      bf16x8 b1 = *(const bf16x8*)&Wt2[(t*16 + m16)*72 + 32 + quad*8];
      acc[t] = __builtin_amdgcn_mfma_f32_16x16x32_bf16(a0, b0, acc[t], 0, 0, 0);
      acc[t] = __builtin_amdgcn_mfma_f32_16x16x32_bf16(a1, b1, acc[t], 0, 0, 0);
    }
  }
  int robase = blockIdx.x*64 + w*16 + quad*4;
  if(m.ep == 3){
    float v[4][4], n2[4] = {0,0,0,0};
    #pragma unroll
    for(int t = 0; t < 4; t++){
      float bv = m.b[t*16 + m16];
      #pragma unroll
      for(int r = 0; r < 4; r++){ v[t][r] = acc[t][r] + bv; n2[r] = fmaf(v[t][r], v[t][r], n2[r]); }
    }
    #pragma unroll
    for(int d = 8; d >= 1; d >>= 1){
      #pragma unroll
      for(int r = 0; r < 4; r++) n2[r] += __shfl_xor(n2[r], d, 64);
    }
    float inv[4];
    #pragma unroll
    for(int r = 0; r < 4; r++) inv[r] = 1.0f / fmaxf(sqrtf(n2[r]), 1e-12f);
    #pragma unroll
    for(int t = 0; t < 4; t++){
      #pragma unroll
      for(int r = 0; r < 4; r++){
        int ro = robase + r;
        if(ro < N) m.C[(size_t)ro*64 + t*16 + m16] = f2bf(fmaxf(v[t][r]*inv[r], 0.f));
      }
    }
    return;
  }
  // ep == 1: BN + relu
  #pragma unroll
  for(int t = 0; t < 4; t++){
    int col = t*16 + m16;
    float bv = m.b[col];
    float gm = m.p1[col]*rsqrtf(1.0f + 1e-5f);
    float be = m.p2[col];
    #pragma unroll
    for(int r = 0; r < 4; r++){
      int ro = robase + r;
      if(ro < N){
        m.C[(size_t)ro*64 + col] = f2bf(fmaxf((acc[t][r] + bv)*gm + be, 0.f));
      }
    }
  }
}

// ---------------- final: GCN2 mm + SAGE2 dual mm + L2norm + GAT2 add + gate combine ----------------
__global__ __launch_bounds__(256) void k_mm_final(
    const unsigned short* __restrict__ A2agg, const unsigned short* __restrict__ wb_gcn2,
    const float* __restrict__ gcn_b2,
    const unsigned short* __restrict__ S2agg, const unsigned short* __restrict__ wb_wl2,
    const float* __restrict__ bl2,
    const unsigned short* __restrict__ s1, const unsigned short* __restrict__ wb_wr2,
    const unsigned short* __restrict__ T2, const float* __restrict__ gat_b2,
    const float* __restrict__ gatew, float* __restrict__ out, int N){
  __shared__ unsigned short W1s[64*72];
  __shared__ unsigned short W2s[64*72];
  __shared__ unsigned short W3s[64*72];
  int tid = threadIdx.x;
  stage_tab(W1s, wb_gcn2, tid);
  stage_tab(W2s, wb_wl2, tid);
  stage_tab(W3s, wb_wr2, tid);
  __syncthreads();
  int w = tid >> 6, lane = tid & 63, quad = lane >> 4, m16 = lane & 15;
  int rowa = blockIdx.x*64 + w*16 + m16;
  int rowc = rowa < N ? rowa : N - 1;
  f32x4 accg[4], accs[4];
  #pragma unroll
  for(int t = 0; t < 4; t++){
    accg[t][0]=0.f; accg[t][1]=0.f; accg[t][2]=0.f; accg[t][3]=0.f;
    accs[t][0]=0.f; accs[t][1]=0.f; accs[t][2]=0.f; accs[t][3]=0.f;
  }
  {
    bf16x8 a0 = *(const bf16x8*)&A2agg[(size_t)rowc*64 + quad*8];
    bf16x8 a1 = *(const bf16x8*)&A2agg[(size_t)rowc*64 + 32 + quad*8];
    #pragma unroll
    for(int t = 0; t < 4; t++){
      bf16x8 b0 = *(const bf16x8*)&W1s[(t*16 + m16)*72 + quad*8];
      bf16x8 b1 = *(const bf16x8*)&W1s[(t*16 + m16)*72 + 32 + quad*8];
      accg[t] = __builtin_amdgcn_mfma_f32_16x16x32_bf16(a0, b0, accg[t], 0, 0, 0);
      accg[t] = __builtin_amdgcn_mfma_f32_16x16x32_bf16(a1, b1, accg[t], 0, 0, 0);
    }
  }
  {
    bf16x8 a0 = *(const bf16x8*)&S2agg[(size_t)rowc*64 + quad*8];
    bf16x8 a1 = *(const bf16x8*)&S2agg[(size_t)rowc*64 + 32 + quad*8];
    #pragma unroll
    for(int t = 0; t < 4; t++){
      bf16x8 b0 = *(const bf16x8*)&W2s[(t*16 + m16)*72 + quad*8];
      bf16x8 b1 = *(const bf16x8*)&W2s[(t*16 + m16)*72 + 32 + quad*8];
      accs[t] = __builtin_amdgcn_mfma_f32_16x16x32_bf16(a0, b0, accs[t], 0, 0, 0);
      accs[t] = __builtin_amdgcn_mfma_f32_16x16x32_bf16(a1, b1, accs[t], 0, 0, 0);
    }
  }
  {
    bf16x8 a0 = *(const bf16x8*)&s1[(size_t)rowc*64 + quad*8];
    bf16x8 a1 = *(const bf16x8*)&s1[(size_t)rowc*64 + 32 + quad*8];
    #pragma unroll
    for(int t = 0; t < 4; t++){
      bf16x8 b0 = *(const bf16x8*)&W3s[(t*16 + m16)*72 + quad*8];
      bf16x8 b1 = *(const bf16x8*)&W3s[(t*16 + m16)*72 + 32 + quad*8];
      accs[t] = __builtin_amdgcn_mfma_f32_16x16x32_bf16(a0, b0, accs[t], 0, 0, 0);
      accs[t] = __builtin_amdgcn_mfma_f32_16x16x32_bf16(a1, b1, accs[t], 0, 0, 0);
    }
  }
  // epilogue
  float w0 = gatew[0], w1 = gatew[1], w2 = gatew[2];
  int robase = blockIdx.x*64 + w*16 + quad*4;
  float vs[4][4], n2[4] = {0,0,0,0};
  #pragma unroll
  for(int t = 0; t < 4; t++){
    float bsv = bl2[t*16 + m16];
    #pragma unroll
    for(int r = 0; r < 4; r++){ vs[t][r] = accs[t][r] + bsv; n2[r] = fmaf(vs[t][r], vs[t][r], n2[r]); }
  }
  #pragma unroll
  for(int d = 8; d >= 1; d >>= 1){
    #pragma unroll
    for(int r = 0; r < 4; r++) n2[r] += __shfl_xor(n2[r], d, 64);
  }
  float inv[4];
  #pragma unroll
  for(int r = 0; r < 4; r++) inv[r] = 1.0f / fmaxf(sqrtf(n2[r]), 1e-12f);
  #pragma unroll
  for(int t = 0; t < 4; t++){
    int col = t*16 + m16;
    float bg = gcn_b2[col], bt = gat_b2[col];
    #pragma unroll
    for(int r = 0; r < 4; r++){
      int ro = robase + r;
      if(ro < N){
        float t2 = bflo((unsigned int)T2[(size_t)ro*64 + col]);
        out[(size_t)ro*64 + col] = w0*(accg[t][r] + bg) + w1*(t2 + bt) + w2*vs[t][r]*inv[r];
      }
    }
  }
}

// ---------------- host ----------------
extern "C" void kernel_launch(void* const* d_in, const int* in_sizes, int n_in,
                              void* d_out, int out_size, void* d_ws, size_t ws_size,
                              hipStream_t stream){
  const float* x        = (const float*)d_in[0];
  const int*   ei       = (const int*)d_in[1];
  const int*   row      = ei;
  const int*   col      = ei + NE;
  const float* gate_w1  = (const float*)d_in[2];
  const float* gate_b1  = (const float*)d_in[3];
  const float* gate_w2  = (const float*)d_in[4];
  const float* gate_b2  = (const float*)d_in[5];
  const float* gcn_w1   = (const float*)d_in[6];
  const float* gcn_b1   = (const float*)d_in[7];
  const float* bn_gamma = (const float*)d_in[8];
  const float* bn_beta  = (const float*)d_in[9];
  const float* gcn_w2   = (const float*)d_in[10];
  const float* gcn_b2   = (const float*)d_in[11];
  const float* gat_w1   = (const float*)d_in[12];
  const float* gat_as1  = (const float*)d_in[13];
  const float* gat_ad1  = (const float*)d_in[14];
  const float* gat_b1   = (const float*)d_in[15];
  const float* gat_w2   = (const float*)d_in[16];
  const float* gat_as2  = (const float*)d_in[17];
  const float* gat_ad2  = (const float*)d_in[18];
  const float* gat_b2   = (const float*)d_in[19];
  const float* sage_wl1 = (const float*)d_in[20];
  const float* sage_bl1 = (const float*)d_in[21];
  const float* sage_wr1 = (const float*)d_in[22];
  const float* sage_wl2 = (const float*)d_in[23];
  const float* sage_bl2 = (const float*)d_in[24];
  const float* sage_wr2 = (const float*)d_in[25];
  float* out = (float*)d_out;

  char* wp = (char*)d_ws;
  auto alloc = [&](size_t bytes)->char*{ char* p = wp; wp += (bytes + 255) & ~(size_t)255; return p; };
  // zero-init region (contiguous): cnt, cursor, gsum, total
  int*   cnt    = (int*)  alloc((size_t)NN*4);
  int*   cursor = (int*)  alloc((size_t)NN*4);
  float* gsum   = (float*)alloc(64*4);
  int*   total  = (int*)  alloc(256);
  size_t zbytes = (size_t)(wp - (char*)cnt);
  int*   offs   = (int*)  alloc((size_t)NN*4);
  int*   csr    = (int*)  alloc((size_t)NE*4);
  float* dis    = (float*)alloc((size_t)NN*4);
  float* invc   = (float*)alloc((size_t)NN*4);
  float* gatew  = (float*)alloc(16);
  float* wsd    = (float*)alloc(64*8*4);
  float* asrc1  = (float*)alloc((size_t)NN*4*4);
  float* adst1  = (float*)alloc((size_t)NN*4*4);
  float* asrc2  = (float*)alloc((size_t)NN*4);
  float* adst2  = (float*)alloc((size_t)NN*4);
  float* wvE1   = (float*)alloc((size_t)NE*4*4);
  float* rden1  = (float*)alloc((size_t)NN*4*4);
  float* wvS1   = (float*)alloc((size_t)NN*4*4);
  float* wvE2   = (float*)alloc((size_t)NE*4);
  float* rden2  = (float*)alloc((size_t)NN*4);
  float* wvS2   = (float*)alloc((size_t)NN*4);
  unsigned short* xb     = (unsigned short*)alloc((size_t)NN*64*2);
  unsigned short* z      = (unsigned short*)alloc((size_t)NN*256*2);
  unsigned short* agcnx  = (unsigned short*)alloc((size_t)NN*64*2);
  unsigned short* asagex = (unsigned short*)alloc((size_t)NN*64*2);
  unsigned short* a1     = (unsigned short*)alloc((size_t)NN*64*2);
  unsigned short* s1     = (unsigned short*)alloc((size_t)NN*64*2);
  unsigned short* h2     = (unsigned short*)alloc((size_t)NN*64*2);
  unsigned short* A2agg  = (unsigned short*)alloc((size_t)NN*64*2);
  unsigned short* S2agg  = (unsigned short*)alloc((size_t)NN*64*2);
  unsigned short* T2     = (unsigned short*)alloc((size_t)NN*64*2);
  // packed bf16 weights (B-operand layout [n][K])
  unsigned short* wb_gcn1 = (unsigned short*)alloc((size_t)64*64*2);
  unsigned short* wb_wl1  = (unsigned short*)alloc((size_t)64*64*2);
  unsigned short* wb_wr1  = (unsigned short*)alloc((size_t)64*64*2);
  unsigned short* wb_gat1 = (unsigned short*)alloc((size_t)256*64*2);
  unsigned short* wb_gat2 = (unsigned short*)alloc((size_t)64*256*2);
  unsigned short* wb_gcn2 = (unsigned short*)alloc((size_t)64*64*2);
  unsigned short* wb_wl2  = (unsigned short*)alloc((size_t)64*64*2);
  unsigned short* wb_wr2  = (unsigned short*)alloc((size_t)64*64*2);

  hipMemsetAsync(cnt, 0, zbytes, stream);

  const int gN  = (NN + 63) / 64;   // 782
  const int g4  = NN / 4;           // 12500
  const int g16 = NN / 16;          // 3125
  const int gA  = (NN + 255) / 256; // 196

  // pack weights once into bf16 B-fragment layout
  {
    PKP pk = {};
    pk.s[0]  = {gcn_w1,   wb_gcn1,            6, 64,  0};
    pk.s[1]  = {sage_wl1, wb_wl1,             6, 64,  0};
    pk.s[2]  = {sage_wr1, wb_wr1,             6, 64,  0};
    pk.s[3]  = {gat_w1,   wb_gat1 + 0*64*64,  6, 256, 0};
    pk.s[4]  = {gat_w1,   wb_gat1 + 1*64*64,  6, 256, 64};
    pk.s[5]  = {gat_w1,   wb_gat1 + 2*64*64,  6, 256, 128};
    pk.s[6]  = {gat_w1,   wb_gat1 + 3*64*64,  6, 256, 192};
    pk.s[7]  = {gat_w2,   wb_gat2,            8, 64,  0};
    pk.s[8]  = {gcn_w2,   wb_gcn2,            6, 64,  0};
    pk.s[9]  = {sage_wl2, wb_wl2,             6, 64,  0};
    pk.s[10] = {sage_wr2, wb_wr2,             6, 64,  0};
    k_packw<<<11, 256, 0, stream>>>(pk);
  }

  k_count<<<(NE+255)/256, 256, 0, stream>>>(col, cnt, NE);
  k_alloc<<<gA, 256, 0, stream>>>(cnt, offs, dis, invc, total, NN);
  k_fill <<<(NE+255)/256, 256, 0, stream>>>(row, col, offs, cursor, csr, NE);
  k_castsum<<<256, 256, 0, stream>>>(x, xb, gsum, NN);
  k_gate  <<<1, 64, 0, stream>>>(gsum, gate_w1, gate_b1, gate_w2, gate_b2, gatew);
  k_fold1 <<<1, 256, 0, stream>>>(gat_w1, gat_as1, gat_ad1, wsd);
  k_attdotx<<<g16, 256, 0, stream>>>(xb, wsd, asrc1, adst1, NN);
  k_edgew1<<<g4, 256, 0, stream>>>(asrc1, adst1, offs, cnt, csr, wvE1, rden1, wvS1, NN);

  // ---- layer-1 one-pass pre-aggregation over xb ----
  k_aggx<<<g4, 256, 0, stream>>>(xb, wvE1, rden1, wvS1, dis, invc, offs, cnt, csr,
                                 z, agcnx, asagex, NN);

  // ---- fused GAT layer1+layer2 (gath never materialized) ----
  k_gat12<<<gN, 256, 0, stream>>>(z, wb_gat1, gat_b1, wb_gat2, gat_as2, gat_ad2,
                                  h2, asrc2, adst2, NN);

  // ---- GCN + SAGE layer-1 matmuls (one dispatch, 2 segments) ----
  {
    MMP p = {};
    p.N = NN;
    p.e[0] = {agcnx, wb_gcn1, nullptr, nullptr, a1, gcn_b1, bn_gamma, bn_beta, 1};
    p.e[1] = {asagex, wb_wl1, xb, wb_wr1, s1, sage_bl1, nullptr, nullptr, 3};
    k_mm_mfma<<<dim3(gN,2), 256, 0, stream>>>(p);
  }

  k_edgew2<<<g4, 256, 0, stream>>>(asrc2, adst2, offs, cnt, csr, wvE2, rden2, wvS2, NN);

  // ---- layer-2 one-pass pre-aggregation ----
  k_aggf<<<g4, 256, 0, stream>>>(a1, s1, h2, wvE2, rden2, wvS2, dis, invc,
                                 offs, cnt, csr, A2agg, S2agg, T2, NN);

  // ---- final matmuls + gate combine ----
  k_mm_final<<<gN, 256, 0, stream>>>(A2agg, wb_gcn2, gcn_b2, S2agg, wb_wl2, sage_bl2,
                                     s1, wb_wr2, T2, gat_b2, gatew, out, NN);
}

// Round 3
// 361.863 us; speedup vs baseline: 1.1017x; 1.0306x over previous
//
#include <hip/hip_runtime.h>
#include <hip/hip_bf16.h>
#include <math.h>

#define NN 50000
#define NE 400000

typedef __attribute__((ext_vector_type(8))) short bf16x8;
typedef __attribute__((ext_vector_type(4))) float f32x4;

// ---------------- helpers ----------------
__device__ __forceinline__ float lrelu(float v){ return v > 0.f ? v : 0.2f*v; }
__device__ __forceinline__ float elu1(float v){ return v > 0.f ? v : expm1f(v); }
__device__ __forceinline__ float bflo(unsigned int u){ return __uint_as_float(u << 16); }
__device__ __forceinline__ float bfhi(unsigned int u){ return __uint_as_float(u & 0xffff0000u); }
__device__ __forceinline__ unsigned short f2bf(float f){
  __hip_bfloat16 h = __float2bfloat16(f);
  return *(unsigned short*)&h;
}
__device__ __forceinline__ unsigned int pack2(float lo, float hi){
  return (unsigned int)f2bf(lo) | ((unsigned int)f2bf(hi) << 16);
}

// stage a packed bf16 [64][64] table into LDS with pitch 72 (2-way-free reads)
__device__ __forceinline__ void stage_tab(unsigned short* Wt, const unsigned short* Wb, int tid){
  #pragma unroll
  for(int s = 0; s < 2; s++){
    int c = tid + s*256;           // 512 chunks of 8 elems
    int n = c >> 3, ko = (c & 7)*8;
    *(bf16x8*)&Wt[n*72 + ko] = *(const bf16x8*)&Wb[n*64 + ko];
  }
}

// ---------------- CSR build ----------------
__global__ void k_count(const int* __restrict__ col, int* __restrict__ cnt, int E){
  int e = blockIdx.x*blockDim.x + threadIdx.x;
  if(e < E) atomicAdd(&cnt[col[e]], 1);
}

__global__ void k_alloc(const int* __restrict__ cnt, int* __restrict__ offs,
                        float* __restrict__ dis, float* __restrict__ invc,
                        int* __restrict__ total, int N){
  int i = blockIdx.x*blockDim.x + threadIdx.x;
  int lane = threadIdx.x & 63;
  int v = (i < N) ? cnt[i] : 0;
  int x = v;
  #pragma unroll
  for(int d = 1; d < 64; d <<= 1){ int t = __shfl_up(x, d, 64); if(lane >= d) x += t; }
  int base = 0;
  if(lane == 63 && x > 0) base = atomicAdd(total, x);
  base = __shfl(base, 63, 64);
  if(i < N){
    offs[i] = base + x - v;
    dis[i]  = 1.0f / sqrtf((float)(v + 1));
    invc[i] = 1.0f / fmaxf((float)v, 1.0f);
  }
}

__global__ void k_fill(const int* __restrict__ row, const int* __restrict__ col,
                       const int* __restrict__ offs, int* __restrict__ cursor,
                       int* __restrict__ csr, int E){
  int e = blockIdx.x*blockDim.x + threadIdx.x;
  if(e < E){
    int c = col[e];
    int pos = offs[c] + atomicAdd(&cursor[c], 1);
    csr[pos] = row[e];
  }
}

// ---------------- pack weights to bf16, B-fragment layout [n][k] ----------------
struct PKS { const float* src; unsigned short* dst; int kshift; int ldw; int col0; };
struct PKP { PKS s[11]; };

__global__ void k_packw(PKP p){
  PKS s = p.s[blockIdx.x];
  int K = 1 << s.kshift;
  int total = K << 6;            // 64 output columns (n) x K
  for(int idx = threadIdx.x; idx < total; idx += 256){
    int n = idx >> s.kshift, k = idx & (K - 1);
    s.dst[idx] = f2bf(s.src[(size_t)k*s.ldw + s.col0 + n]);
  }
}

// ---------------- cast x -> bf16 + column sums for gate ----------------
__global__ void k_castsum(const float* __restrict__ x, unsigned short* __restrict__ xb,
                          float* __restrict__ gsum, int N){
  __shared__ float part[4][64];
  int lane = threadIdx.x & 63, w = threadIdx.x >> 6;
  float s = 0.f;
  for(int r = blockIdx.x*4 + w; r < N; r += gridDim.x*4){
    float v = x[(size_t)r*64 + lane];
    xb[(size_t)r*64 + lane] = f2bf(v);
    s += v;
  }
  part[w][lane] = s;
  __syncthreads();
  if(w == 0) atomicAdd(&gsum[lane], part[0][lane]+part[1][lane]+part[2][lane]+part[3][lane]);
}

__global__ void k_gate(const float* __restrict__ gsum,
                       const float* __restrict__ w1, const float* __restrict__ b1,
                       const float* __restrict__ w2, const float* __restrict__ b2,
                       float* __restrict__ gatew){
  __shared__ float g[64]; __shared__ float hid[64]; __shared__ float lg[3];
  int t = threadIdx.x;
  g[t] = gsum[t] * (1.0f/(float)NN);
  __syncthreads();
  float acc = b1[t];
  for(int i = 0; i < 64; i++) acc += g[i]*w1[i*64 + t];
  hid[t] = fmaxf(acc, 0.f);
  __syncthreads();
  if(t < 3){
    float a = b2[t];
    for(int j = 0; j < 64; j++) a += hid[j]*w2[j*3 + t];
    lg[t] = a;
  }
  __syncthreads();
  if(t == 0){
    float m = fmaxf(lg[0], fmaxf(lg[1], lg[2]));
    float e0 = expf(lg[0]-m), e1 = expf(lg[1]-m), e2 = expf(lg[2]-m);
    float s = e0 + e1 + e2;
    gatew[0] = e0/s; gatew[1] = e1/s; gatew[2] = e2/s;
  }
}

// ---------------- fold GAT1 attention vectors through W ----------------
__global__ void k_fold1(const float* __restrict__ w1, const float* __restrict__ as,
                        const float* __restrict__ ad, float* __restrict__ wsd){
  int t = threadIdx.x;            // 256
  int k = t & 63, h = t >> 6;
  float ssrc = 0.f, sdst = 0.f;
  for(int c = 0; c < 64; c++){
    float w = w1[k*256 + h*64 + c];
    ssrc += w * as[h*64 + c];
    sdst += w * ad[h*64 + c];
  }
  wsd[k*8 + h] = ssrc;
  wsd[k*8 + 4 + h] = sdst;
}

// ---------------- asrc1/adst1 = xb @ Wsd  (16 lanes per node) ----------------
__global__ void k_attdotx(const unsigned short* __restrict__ xb, const float* __restrict__ wsd,
                          float* __restrict__ asrc, float* __restrict__ adst, int N){
  __shared__ float ws[64*8];
  int tid = threadIdx.x;
  ws[tid] = wsd[tid];
  ws[tid + 256] = wsd[tid + 256];
  __syncthreads();
  int node = blockIdx.x*16 + (tid >> 4);
  int l = tid & 15;
  if(node >= N) return;
  uint2 u = *(const uint2*)&xb[(size_t)node*64 + l*4];
  float v0 = bflo(u.x), v1 = bfhi(u.x), v2 = bflo(u.y), v3 = bfhi(u.y);
  float s[8];
  #pragma unroll
  for(int h = 0; h < 8; h++){
    s[h] = v0*ws[(l*4+0)*8+h] + v1*ws[(l*4+1)*8+h] + v2*ws[(l*4+2)*8+h] + v3*ws[(l*4+3)*8+h];
  }
  #pragma unroll
  for(int d = 8; d >= 1; d >>= 1){
    #pragma unroll
    for(int h = 0; h < 8; h++) s[h] += __shfl_xor(s[h], d, 16);
  }
  if(l == 0){
    float4 o1; o1.x = s[0]; o1.y = s[1]; o1.z = s[2]; o1.w = s[3];
    float4 o2; o2.x = s[4]; o2.y = s[5]; o2.z = s[6]; o2.w = s[7];
    *(float4*)&asrc[node*4] = o1;
    *(float4*)&adst[node*4] = o2;
  }
}

// ---------------- GAT edge weights ----------------
__global__ void k_edgew1(const float* __restrict__ asrc, const float* __restrict__ adst,
                         const int* __restrict__ offs, const int* __restrict__ cnt,
                         const int* __restrict__ csr,
                         float* __restrict__ wvE, float* __restrict__ rdenN,
                         float* __restrict__ wvS, int N){
  int node = blockIdx.x*4 + (threadIdx.x >> 6);
  int lane = threadIdx.x & 63;
  if(node >= N) return;
  float4 ad = *(const float4*)&adst[node*4];
  float a0 = 0.f, a1 = 0.f, a2 = 0.f, a3 = 0.f;
  int e0 = offs[node], e1 = e0 + cnt[node];
  for(int e = e0 + lane; e < e1; e += 64){
    int s = csr[e];
    float4 as = *(const float4*)&asrc[s*4];
    float4 w;
    w.x = expf(lrelu(as.x + ad.x));
    w.y = expf(lrelu(as.y + ad.y));
    w.z = expf(lrelu(as.z + ad.z));
    w.w = expf(lrelu(as.w + ad.w));
    a0 += w.x; a1 += w.y; a2 += w.z; a3 += w.w;
    *(float4*)&wvE[(size_t)e*4] = w;
  }
  #pragma unroll
  for(int d = 32; d >= 1; d >>= 1){
    a0 += __shfl_xor(a0, d, 64); a1 += __shfl_xor(a1, d, 64);
    a2 += __shfl_xor(a2, d, 64); a3 += __shfl_xor(a3, d, 64);
  }
  float4 asl = *(const float4*)&asrc[node*4];
  float4 ws;
  ws.x = expf(lrelu(asl.x + ad.x));
  ws.y = expf(lrelu(asl.y + ad.y));
  ws.z = expf(lrelu(asl.z + ad.z));
  ws.w = expf(lrelu(asl.w + ad.w));
  if(lane == 0){
    float4 rd;
    rd.x = 1.0f/(a0 + ws.x); rd.y = 1.0f/(a1 + ws.y);
    rd.z = 1.0f/(a2 + ws.z); rd.w = 1.0f/(a3 + ws.w);
    *(float4*)&rdenN[node*4] = rd;
    *(float4*)&wvS[node*4] = ws;
  }
}

__global__ void k_edgew2(const float* __restrict__ asrc, const float* __restrict__ adst,
                         const int* __restrict__ offs, const int* __restrict__ cnt,
                         const int* __restrict__ csr,
                         float* __restrict__ wvE, float* __restrict__ rdenN,
                         float* __restrict__ wvS, int N){
  int node = blockIdx.x*4 + (threadIdx.x >> 6);
  int lane = threadIdx.x & 63;
  if(node >= N) return;
  float ad = adst[node];
  float acc = 0.f;
  int e0 = offs[node], e1 = e0 + cnt[node];
  for(int e = e0 + lane; e < e1; e += 64){
    float w = expf(lrelu(asrc[csr[e]] + ad));
    acc += w;
    wvE[e] = w;
  }
  #pragma unroll
  for(int d = 32; d >= 1; d >>= 1) acc += __shfl_xor(acc, d, 64);
  float ws = expf(lrelu(asrc[node] + ad));
  if(lane == 0){
    rdenN[node] = 1.0f/(acc + ws);
    wvS[node] = ws;
  }
}

// ---------------- layer-1 one-pass pre-aggregation over xb ----------------
__global__ void k_aggx(const unsigned short* __restrict__ xb,
                       const float* __restrict__ wvE, const float* __restrict__ rden,
                       const float* __restrict__ wvS,
                       const float* __restrict__ dis, const float* __restrict__ invc,
                       const int* __restrict__ offs, const int* __restrict__ cnt,
                       const int* __restrict__ csr,
                       unsigned short* __restrict__ z, unsigned short* __restrict__ agcnx,
                       unsigned short* __restrict__ asagex, int N){
  int node = blockIdx.x*4 + (threadIdx.x >> 6);
  int lane = threadIdx.x & 63;
  if(node >= N) return;
  int half = lane >> 5, subl = lane & 31;      // subl*2, subl*2+1 channels
  float zg[4][2] = {{0,0},{0,0},{0,0},{0,0}};
  float gg[2] = {0,0}, ssv[2] = {0,0};
  int e0 = offs[node], e1 = e0 + cnt[node];
  #pragma unroll 2
  for(int e = e0 + half; e < e1; e += 2){
    int s = csr[e];
    float4 w4 = *(const float4*)&wvE[(size_t)e*4];
    float ds = dis[s];
    unsigned int u = *(const unsigned int*)&xb[(size_t)s*64 + subl*2];
    float xl = bflo(u), xh = bfhi(u);
    zg[0][0] = fmaf(w4.x, xl, zg[0][0]); zg[0][1] = fmaf(w4.x, xh, zg[0][1]);
    zg[1][0] = fmaf(w4.y, xl, zg[1][0]); zg[1][1] = fmaf(w4.y, xh, zg[1][1]);
    zg[2][0] = fmaf(w4.z, xl, zg[2][0]); zg[2][1] = fmaf(w4.z, xh, zg[2][1]);
    zg[3][0] = fmaf(w4.w, xl, zg[3][0]); zg[3][1] = fmaf(w4.w, xh, zg[3][1]);
    gg[0] = fmaf(ds, xl, gg[0]); gg[1] = fmaf(ds, xh, gg[1]);
    ssv[0] += xl; ssv[1] += xh;
  }
  #pragma unroll
  for(int h = 0; h < 4; h++){
    zg[h][0] += __shfl_xor(zg[h][0], 32, 64);
    zg[h][1] += __shfl_xor(zg[h][1], 32, 64);
  }
  gg[0] += __shfl_xor(gg[0], 32, 64); gg[1] += __shfl_xor(gg[1], 32, 64);
  ssv[0] += __shfl_xor(ssv[0], 32, 64); ssv[1] += __shfl_xor(ssv[1], 32, 64);
  if(half == 0){
    unsigned int un = *(const unsigned int*)&xb[(size_t)node*64 + subl*2];
    float xl = bflo(un), xh = bfhi(un);
    float4 ws4 = *(const float4*)&wvS[node*4];
    float4 rd4 = *(const float4*)&rden[node*4];
    unsigned int* zp = (unsigned int*)&z[(size_t)node*256 + subl*2];
    zp[0]   = pack2((zg[0][0] + ws4.x*xl)*rd4.x, (zg[0][1] + ws4.x*xh)*rd4.x);
    zp[32]  = pack2((zg[1][0] + ws4.y*xl)*rd4.y, (zg[1][1] + ws4.y*xh)*rd4.y);
    zp[64]  = pack2((zg[2][0] + ws4.z*xl)*rd4.z, (zg[2][1] + ws4.z*xh)*rd4.z);
    zp[96]  = pack2((zg[3][0] + ws4.w*xl)*rd4.w, (zg[3][1] + ws4.w*xh)*rd4.w);
    float dc = dis[node], ic = invc[node];
    *(unsigned int*)&agcnx[(size_t)node*64 + subl*2] =
        pack2(dc*fmaf(dc, xl, gg[0]), dc*fmaf(dc, xh, gg[1]));
    *(unsigned int*)&asagex[(size_t)node*64 + subl*2] = pack2(ssv[0]*ic, ssv[1]*ic);
  }
}

// ---------------- layer-2 one-pass pre-aggregation over a1 / s1 / h2 ----------------
__global__ void k_aggf(const unsigned short* __restrict__ a1, const unsigned short* __restrict__ s1,
                       const unsigned short* __restrict__ h2,
                       const float* __restrict__ wvE, const float* __restrict__ rden,
                       const float* __restrict__ wvS,
                       const float* __restrict__ dis, const float* __restrict__ invc,
                       const int* __restrict__ offs, const int* __restrict__ cnt,
                       const int* __restrict__ csr,
                       unsigned short* __restrict__ A2agg, unsigned short* __restrict__ S2agg,
                       unsigned short* __restrict__ T2, int N){
  int node = blockIdx.x*4 + (threadIdx.x >> 6);
  int lane = threadIdx.x & 63;
  if(node >= N) return;
  int half = lane >> 5, subl = lane & 31;
  float aa[2] = {0,0}, ss[2] = {0,0}, tt[2] = {0,0};
  int e0 = offs[node], e1 = e0 + cnt[node];
  #pragma unroll 2
  for(int e = e0 + half; e < e1; e += 2){
    int s = csr[e];
    float ds = dis[s];
    float wv = wvE[e];
    unsigned int ua = *(const unsigned int*)&a1[(size_t)s*64 + subl*2];
    unsigned int us = *(const unsigned int*)&s1[(size_t)s*64 + subl*2];
    unsigned int uh = *(const unsigned int*)&h2[(size_t)s*64 + subl*2];
    aa[0] = fmaf(ds, bflo(ua), aa[0]); aa[1] = fmaf(ds, bfhi(ua), aa[1]);
    ss[0] += bflo(us); ss[1] += bfhi(us);
    tt[0] = fmaf(wv, bflo(uh), tt[0]); tt[1] = fmaf(wv, bfhi(uh), tt[1]);
  }
  aa[0] += __shfl_xor(aa[0], 32, 64); aa[1] += __shfl_xor(aa[1], 32, 64);
  ss[0] += __shfl_xor(ss[0], 32, 64); ss[1] += __shfl_xor(ss[1], 32, 64);
  tt[0] += __shfl_xor(tt[0], 32, 64); tt[1] += __shfl_xor(tt[1], 32, 64);
  if(half == 0){
    unsigned int uan = *(const unsigned int*)&a1[(size_t)node*64 + subl*2];
    unsigned int uhn = *(const unsigned int*)&h2[(size_t)node*64 + subl*2];
    float dc = dis[node], ic = invc[node];
    float rd = rden[node], wss = wvS[node];
    *(unsigned int*)&A2agg[(size_t)node*64 + subl*2] =
        pack2(dc*fmaf(dc, bflo(uan), aa[0]), dc*fmaf(dc, bfhi(uan), aa[1]));
    *(unsigned int*)&S2agg[(size_t)node*64 + subl*2] = pack2(ss[0]*ic, ss[1]*ic);
    *(unsigned int*)&T2[(size_t)node*64 + subl*2] =
        pack2(fmaf(wss, bflo(uhn), tt[0])*rd, fmaf(wss, bfhi(uhn), tt[1])*rd);
  }
}

// ---------------- fused dispatch: y=0 GAT1+2, y=1 GCN1 mm, y=2 SAGE1 mm ----------------
struct MME {
  const unsigned short* A; const unsigned short* Wb;
  const unsigned short* A2; const unsigned short* Wb2;  // optional second segment (K2=64)
  unsigned short* C;
  const float* b; const float* p1; const float* p2;
  int ep;                                               // 1 = BN+relu; 3 = sage
};
struct FSP {
  // GAT path
  const unsigned short* z; const unsigned short* wb1; const float* b1;
  const unsigned short* wb2; const float* as2; const float* ad2;
  unsigned short* h2; float* asrc2; float* adst2;
  // mm path
  MME mm[2];
  int N;
};

__global__ __launch_bounds__(256, 4) void k_fused1(FSP p){
  __shared__ unsigned short smem[16896];   // GAT: GH[64][264]; mm: 2x [64][72] tables
  const int N = p.N;
  int tid = threadIdx.x;
  int w = tid >> 6, lane = tid & 63, quad = lane >> 4, m16 = lane & 15;
  int rowa = blockIdx.x*64 + w*16 + m16;
  int rowc = rowa < N ? rowa : N - 1;
  int robase = blockIdx.x*64 + w*16 + quad*4;

  if(blockIdx.y == 0){
    // ================= GAT layer1+layer2, one barrier =================
    unsigned short* GH = smem;             // pitch 264
    int lr = w*16;
    // phase A: all 4 heads, B-frags straight from L1/L2-hot packed table
    #pragma unroll
    for(int h = 0; h < 4; h++){
      bf16x8 a0 = *(const bf16x8*)&p.z[(size_t)rowc*256 + h*64 + quad*8];
      bf16x8 a1 = *(const bf16x8*)&p.z[(size_t)rowc*256 + h*64 + 32 + quad*8];
      f32x4 acc[4];
      #pragma unroll
      for(int t = 0; t < 4; t++){ acc[t][0]=0.f; acc[t][1]=0.f; acc[t][2]=0.f; acc[t][3]=0.f; }
      #pragma unroll
      for(int t = 0; t < 4; t++){
        const unsigned short* wb = p.wb1 + (size_t)h*4096 + (t*16 + m16)*64;
        bf16x8 b0 = *(const bf16x8*)&wb[quad*8];
        bf16x8 b1v = *(const bf16x8*)&wb[32 + quad*8];
        acc[t] = __builtin_amdgcn_mfma_f32_16x16x32_bf16(a0, b0, acc[t], 0, 0, 0);
        acc[t] = __builtin_amdgcn_mfma_f32_16x16x32_bf16(a1, b1v, acc[t], 0, 0, 0);
      }
      #pragma unroll
      for(int t = 0; t < 4; t++){
        float bv = p.b1[h*64 + t*16 + m16];
        #pragma unroll
        for(int r = 0; r < 4; r++){
          GH[(lr + quad*4 + r)*264 + h*64 + t*16 + m16] = f2bf(elu1(acc[t][r] + bv));
        }
      }
    }
    __syncthreads();
    // phase B: GH (64x256) @ W2 (256x64), B from L1/L2-hot table
    f32x4 acc2[4];
    #pragma unroll
    for(int t = 0; t < 4; t++){ acc2[t][0]=0.f; acc2[t][1]=0.f; acc2[t][2]=0.f; acc2[t][3]=0.f; }
    #pragma unroll
    for(int kc = 0; kc < 256; kc += 64){
      bf16x8 a0 = *(const bf16x8*)&GH[(lr + m16)*264 + kc + quad*8];
      bf16x8 a1 = *(const bf16x8*)&GH[(lr + m16)*264 + kc + 32 + quad*8];
      #pragma unroll
      for(int t = 0; t < 4; t++){
        const unsigned short* wb = p.wb2 + (size_t)(t*16 + m16)*256 + kc;
        bf16x8 b0 = *(const bf16x8*)&wb[quad*8];
        bf16x8 b1v = *(const bf16x8*)&wb[32 + quad*8];
        acc2[t] = __builtin_amdgcn_mfma_f32_16x16x32_bf16(a0, b0, acc2[t], 0, 0, 0);
        acc2[t] = __builtin_amdgcn_mfma_f32_16x16x32_bf16(a1, b1v, acc2[t], 0, 0, 0);
      }
    }
    // epilogue: store h2 (bf16) + attention dots
    #pragma unroll
    for(int t = 0; t < 4; t++){
      int col = t*16 + m16;
      #pragma unroll
      for(int r = 0; r < 4; r++){
        int ro = robase + r;
        if(ro < N) p.h2[(size_t)ro*64 + col] = f2bf(acc2[t][r]);
      }
    }
    float ps[4] = {0,0,0,0}, pd[4] = {0,0,0,0};
    #pragma unroll
    for(int t = 0; t < 4; t++){
      int col = t*16 + m16;
      float a_ = p.as2[col], d_ = p.ad2[col];
      #pragma unroll
      for(int r = 0; r < 4; r++){ ps[r] = fmaf(acc2[t][r], a_, ps[r]); pd[r] = fmaf(acc2[t][r], d_, pd[r]); }
    }
    #pragma unroll
    for(int d = 8; d >= 1; d >>= 1){
      #pragma unroll
      for(int r = 0; r < 4; r++){ ps[r] += __shfl_xor(ps[r], d, 64); pd[r] += __shfl_xor(pd[r], d, 64); }
    }
    if(m16 == 0){
      #pragma unroll
      for(int r = 0; r < 4; r++){
        int ro = robase + r;
        if(ro < N){ p.asrc2[ro] = ps[r]; p.adst2[ro] = pd[r]; }
      }
    }
    return;
  }

  // ================= GCN / SAGE layer-1 matmuls (LDS-staged B) =================
  MME m = p.mm[blockIdx.y - 1];
  unsigned short* Wt  = smem;
  unsigned short* Wt2 = smem + 4608;
  stage_tab(Wt, m.Wb, tid);
  if(m.Wb2) stage_tab(Wt2, m.Wb2, tid);
  __syncthreads();
  f32x4 acc[4];
  #pragma unroll
  for(int t = 0; t < 4; t++){ acc[t][0]=0.f; acc[t][1]=0.f; acc[t][2]=0.f; acc[t][3]=0.f; }
  {
    bf16x8 a0 = *(const bf16x8*)&m.A[(size_t)rowc*64 + quad*8];
    bf16x8 a1 = *(const bf16x8*)&m.A[(size_t)rowc*64 + 32 + quad*8];
    #pragma unroll
    for(int t = 0; t < 4; t++){
      bf16x8 b0 = *(const bf16x8*)&Wt[(t*16 + m16)*72 + quad*8];
      bf16x8 b1 = *(const bf16x8*)&Wt[(t*16 + m16)*72 + 32 + quad*8];
      acc[t] = __builtin_amdgcn_mfma_f32_16x16x32_bf16(a0, b0, acc[t], 0, 0, 0);
      acc[t] = __builtin_amdgcn_mfma_f32_16x16x32_bf16(a1, b1, acc[t], 0, 0, 0);
    }
  }
  if(m.A2){
    bf16x8 a0 = *(const bf16x8*)&m.A2[(size_t)rowc*64 + quad*8];
    bf16x8 a1 = *(const bf16x8*)&m.A2[(size_t)rowc*64 + 32 + quad*8];
    #pragma unroll
    for(int t = 0; t < 4; t++){
      bf16x8 b0 = *(const bf16x8*)&Wt2[(t*16 + m16)*72 + quad*8];
      bf16x8 b1 = *(const bf16x8*)&Wt2[(t*16 + m16)*72 + 32 + quad*8];
      acc[t] = __builtin_amdgcn_mfma_f32_16x16x32_bf16(a0, b0, acc[t], 0, 0, 0);
      acc[t] = __builtin_amdgcn_mfma_f32_16x16x32_bf16(a1, b1, acc[t], 0, 0, 0);
    }
  }
  if(m.ep == 3){
    float v[4][4], n2[4] = {0,0,0,0};
    #pragma unroll
    for(int t = 0; t < 4; t++){
      float bv = m.b[t*16 + m16];
      #pragma unroll
      for(int r = 0; r < 4; r++){ v[t][r] = acc[t][r] + bv; n2[r] = fmaf(v[t][r], v[t][r], n2[r]); }
    }
    #pragma unroll
    for(int d = 8; d >= 1; d >>= 1){
      #pragma unroll
      for(int r = 0; r < 4; r++) n2[r] += __shfl_xor(n2[r], d, 64);
    }
    float inv[4];
    #pragma unroll
    for(int r = 0; r < 4; r++) inv[r] = 1.0f / fmaxf(sqrtf(n2[r]), 1e-12f);
    #pragma unroll
    for(int t = 0; t < 4; t++){
      #pragma unroll
      for(int r = 0; r < 4; r++){
        int ro = robase + r;
        if(ro < N) m.C[(size_t)ro*64 + t*16 + m16] = f2bf(fmaxf(v[t][r]*inv[r], 0.f));
      }
    }
    return;
  }
  // ep == 1: BN + relu
  #pragma unroll
  for(int t = 0; t < 4; t++){
    int col = t*16 + m16;
    float bv = m.b[col];
    float gm = m.p1[col]*rsqrtf(1.0f + 1e-5f);
    float be = m.p2[col];
    #pragma unroll
    for(int r = 0; r < 4; r++){
      int ro = robase + r;
      if(ro < N){
        m.C[(size_t)ro*64 + col] = f2bf(fmaxf((acc[t][r] + bv)*gm + be, 0.f));
      }
    }
  }
}

// ---------------- final: GCN2 mm + SAGE2 dual mm + L2norm + GAT2 add + gate combine ----------------
__global__ __launch_bounds__(256) void k_mm_final(
    const unsigned short* __restrict__ A2agg, const unsigned short* __restrict__ wb_gcn2,
    const float* __restrict__ gcn_b2,
    const unsigned short* __restrict__ S2agg, const unsigned short* __restrict__ wb_wl2,
    const float* __restrict__ bl2,
    const unsigned short* __restrict__ s1, const unsigned short* __restrict__ wb_wr2,
    const unsigned short* __restrict__ T2, const float* __restrict__ gat_b2,
    const float* __restrict__ gatew, float* __restrict__ out, int N){
  __shared__ unsigned short W1s[64*72];
  __shared__ unsigned short W2s[64*72];
  __shared__ unsigned short W3s[64*72];
  int tid = threadIdx.x;
  stage_tab(W1s, wb_gcn2, tid);
  stage_tab(W2s, wb_wl2, tid);
  stage_tab(W3s, wb_wr2, tid);
  __syncthreads();
  int w = tid >> 6, lane = tid & 63, quad = lane >> 4, m16 = lane & 15;
  int rowa = blockIdx.x*64 + w*16 + m16;
  int rowc = rowa < N ? rowa : N - 1;
  f32x4 accg[4], accs[4];
  #pragma unroll
  for(int t = 0; t < 4; t++){
    accg[t][0]=0.f; accg[t][1]=0.f; accg[t][2]=0.f; accg[t][3]=0.f;
    accs[t][0]=0.f; accs[t][1]=0.f; accs[t][2]=0.f; accs[t][3]=0.f;
  }
  {
    bf16x8 a0 = *(const bf16x8*)&A2agg[(size_t)rowc*64 + quad*8];
    bf16x8 a1 = *(const bf16x8*)&A2agg[(size_t)rowc*64 + 32 + quad*8];
    #pragma unroll
    for(int t = 0; t < 4; t++){
      bf16x8 b0 = *(const bf16x8*)&W1s[(t*16 + m16)*72 + quad*8];
      bf16x8 b1 = *(const bf16x8*)&W1s[(t*16 + m16)*72 + 32 + quad*8];
      accg[t] = __builtin_amdgcn_mfma_f32_16x16x32_bf16(a0, b0, accg[t], 0, 0, 0);
      accg[t] = __builtin_amdgcn_mfma_f32_16x16x32_bf16(a1, b1, accg[t], 0, 0, 0);
    }
  }
  {
    bf16x8 a0 = *(const bf16x8*)&S2agg[(size_t)rowc*64 + quad*8];
    bf16x8 a1 = *(const bf16x8*)&S2agg[(size_t)rowc*64 + 32 + quad*8];
    #pragma unroll
    for(int t = 0; t < 4; t++){
      bf16x8 b0 = *(const bf16x8*)&W2s[(t*16 + m16)*72 + quad*8];
      bf16x8 b1 = *(const bf16x8*)&W2s[(t*16 + m16)*72 + 32 + quad*8];
      accs[t] = __builtin_amdgcn_mfma_f32_16x16x32_bf16(a0, b0, accs[t], 0, 0, 0);
      accs[t] = __builtin_amdgcn_mfma_f32_16x16x32_bf16(a1, b1, accs[t], 0, 0, 0);
    }
  }
  {
    bf16x8 a0 = *(const bf16x8*)&s1[(size_t)rowc*64 + quad*8];
    bf16x8 a1 = *(const bf16x8*)&s1[(size_t)rowc*64 + 32 + quad*8];
    #pragma unroll
    for(int t = 0; t < 4; t++){
      bf16x8 b0 = *(const bf16x8*)&W3s[(t*16 + m16)*72 + quad*8];
      bf16x8 b1 = *(const bf16x8*)&W3s[(t*16 + m16)*72 + 32 + quad*8];
      accs[t] = __builtin_amdgcn_mfma_f32_16x16x32_bf16(a0, b0, accs[t], 0, 0, 0);
      accs[t] = __builtin_amdgcn_mfma_f32_16x16x32_bf16(a1, b1, accs[t], 0, 0, 0);
    }
  }
  // epilogue
  float w0 = gatew[0], w1 = gatew[1], w2 = gatew[2];
  int robase = blockIdx.x*64 + w*16 + quad*4;
  float vs[4][4], n2[4] = {0,0,0,0};
  #pragma unroll
  for(int t = 0; t < 4; t++){
    float bsv = bl2[t*16 + m16];
    #pragma unroll
    for(int r = 0; r < 4; r++){ vs[t][r] = accs[t][r] + bsv; n2[r] = fmaf(vs[t][r], vs[t][r], n2[r]); }
  }
  #pragma unroll
  for(int d = 8; d >= 1; d >>= 1){
    #pragma unroll
    for(int r = 0; r < 4; r++) n2[r] += __shfl_xor(n2[r], d, 64);
  }
  float inv[4];
  #pragma unroll
  for(int r = 0; r < 4; r++) inv[r] = 1.0f / fmaxf(sqrtf(n2[r]), 1e-12f);
  #pragma unroll
  for(int t = 0; t < 4; t++){
    int col = t*16 + m16;
    float bg = gcn_b2[col], bt = gat_b2[col];
    #pragma unroll
    for(int r = 0; r < 4; r++){
      int ro = robase + r;
      if(ro < N){
        float t2 = bflo((unsigned int)T2[(size_t)ro*64 + col]);
        out[(size_t)ro*64 + col] = w0*(accg[t][r] + bg) + w1*(t2 + bt) + w2*vs[t][r]*inv[r];
      }
    }
  }
}

// ---------------- host ----------------
extern "C" void kernel_launch(void* const* d_in, const int* in_sizes, int n_in,
                              void* d_out, int out_size, void* d_ws, size_t ws_size,
                              hipStream_t stream){
  const float* x        = (const float*)d_in[0];
  const int*   ei       = (const int*)d_in[1];
  const int*   row      = ei;
  const int*   col      = ei + NE;
  const float* gate_w1  = (const float*)d_in[2];
  const float* gate_b1  = (const float*)d_in[3];
  const float* gate_w2  = (const float*)d_in[4];
  const float* gate_b2  = (const float*)d_in[5];
  const float* gcn_w1   = (const float*)d_in[6];
  const float* gcn_b1   = (const float*)d_in[7];
  const float* bn_gamma = (const float*)d_in[8];
  const float* bn_beta  = (const float*)d_in[9];
  const float* gcn_w2   = (const float*)d_in[10];
  const float* gcn_b2   = (const float*)d_in[11];
  const float* gat_w1   = (const float*)d_in[12];
  const float* gat_as1  = (const float*)d_in[13];
  const float* gat_ad1  = (const float*)d_in[14];
  const float* gat_b1   = (const float*)d_in[15];
  const float* gat_w2   = (const float*)d_in[16];
  const float* gat_as2  = (const float*)d_in[17];
  const float* gat_ad2  = (const float*)d_in[18];
  const float* gat_b2   = (const float*)d_in[19];
  const float* sage_wl1 = (const float*)d_in[20];
  const float* sage_bl1 = (const float*)d_in[21];
  const float* sage_wr1 = (const float*)d_in[22];
  const float* sage_wl2 = (const float*)d_in[23];
  const float* sage_bl2 = (const float*)d_in[24];
  const float* sage_wr2 = (const float*)d_in[25];
  float* out = (float*)d_out;

  char* wp = (char*)d_ws;
  auto alloc = [&](size_t bytes)->char*{ char* p = wp; wp += (bytes + 255) & ~(size_t)255; return p; };
  // zero-init region (contiguous): cnt, cursor, gsum, total
  int*   cnt    = (int*)  alloc((size_t)NN*4);
  int*   cursor = (int*)  alloc((size_t)NN*4);
  float* gsum   = (float*)alloc(64*4);
  int*   total  = (int*)  alloc(256);
  size_t zbytes = (size_t)(wp - (char*)cnt);
  int*   offs   = (int*)  alloc((size_t)NN*4);
  int*   csr    = (int*)  alloc((size_t)NE*4);
  float* dis    = (float*)alloc((size_t)NN*4);
  float* invc   = (float*)alloc((size_t)NN*4);
  float* gatew  = (float*)alloc(16);
  float* wsd    = (float*)alloc(64*8*4);
  float* asrc1  = (float*)alloc((size_t)NN*4*4);
  float* adst1  = (float*)alloc((size_t)NN*4*4);
  float* asrc2  = (float*)alloc((size_t)NN*4);
  float* adst2  = (float*)alloc((size_t)NN*4);
  float* wvE1   = (float*)alloc((size_t)NE*4*4);
  float* rden1  = (float*)alloc((size_t)NN*4*4);
  float* wvS1   = (float*)alloc((size_t)NN*4*4);
  float* wvE2   = (float*)alloc((size_t)NE*4);
  float* rden2  = (float*)alloc((size_t)NN*4);
  float* wvS2   = (float*)alloc((size_t)NN*4);
  unsigned short* xb     = (unsigned short*)alloc((size_t)NN*64*2);
  unsigned short* z      = (unsigned short*)alloc((size_t)NN*256*2);
  unsigned short* agcnx  = (unsigned short*)alloc((size_t)NN*64*2);
  unsigned short* asagex = (unsigned short*)alloc((size_t)NN*64*2);
  unsigned short* a1     = (unsigned short*)alloc((size_t)NN*64*2);
  unsigned short* s1     = (unsigned short*)alloc((size_t)NN*64*2);
  unsigned short* h2     = (unsigned short*)alloc((size_t)NN*64*2);
  unsigned short* A2agg  = (unsigned short*)alloc((size_t)NN*64*2);
  unsigned short* S2agg  = (unsigned short*)alloc((size_t)NN*64*2);
  unsigned short* T2     = (unsigned short*)alloc((size_t)NN*64*2);
  // packed bf16 weights (B-operand layout [n][K])
  unsigned short* wb_gcn1 = (unsigned short*)alloc((size_t)64*64*2);
  unsigned short* wb_wl1  = (unsigned short*)alloc((size_t)64*64*2);
  unsigned short* wb_wr1  = (unsigned short*)alloc((size_t)64*64*2);
  unsigned short* wb_gat1 = (unsigned short*)alloc((size_t)256*64*2);
  unsigned short* wb_gat2 = (unsigned short*)alloc((size_t)64*256*2);
  unsigned short* wb_gcn2 = (unsigned short*)alloc((size_t)64*64*2);
  unsigned short* wb_wl2  = (unsigned short*)alloc((size_t)64*64*2);
  unsigned short* wb_wr2  = (unsigned short*)alloc((size_t)64*64*2);

  hipMemsetAsync(cnt, 0, zbytes, stream);

  const int gN  = (NN + 63) / 64;   // 782
  const int g4  = NN / 4;           // 12500
  const int g16 = NN / 16;          // 3125
  const int gA  = (NN + 255) / 256; // 196

  // pack weights once into bf16 B-fragment layout
  {
    PKP pk = {};
    pk.s[0]  = {gcn_w1,   wb_gcn1,            6, 64,  0};
    pk.s[1]  = {sage_wl1, wb_wl1,             6, 64,  0};
    pk.s[2]  = {sage_wr1, wb_wr1,             6, 64,  0};
    pk.s[3]  = {gat_w1,   wb_gat1 + 0*64*64,  6, 256, 0};
    pk.s[4]  = {gat_w1,   wb_gat1 + 1*64*64,  6, 256, 64};
    pk.s[5]  = {gat_w1,   wb_gat1 + 2*64*64,  6, 256, 128};
    pk.s[6]  = {gat_w1,   wb_gat1 + 3*64*64,  6, 256, 192};
    pk.s[7]  = {gat_w2,   wb_gat2,            8, 64,  0};
    pk.s[8]  = {gcn_w2,   wb_gcn2,            6, 64,  0};
    pk.s[9]  = {sage_wl2, wb_wl2,             6, 64,  0};
    pk.s[10] = {sage_wr2, wb_wr2,             6, 64,  0};
    k_packw<<<11, 256, 0, stream>>>(pk);
  }

  k_count<<<(NE+255)/256, 256, 0, stream>>>(col, cnt, NE);
  k_alloc<<<gA, 256, 0, stream>>>(cnt, offs, dis, invc, total, NN);
  k_fill <<<(NE+255)/256, 256, 0, stream>>>(row, col, offs, cursor, csr, NE);
  k_castsum<<<256, 256, 0, stream>>>(x, xb, gsum, NN);
  k_gate  <<<1, 64, 0, stream>>>(gsum, gate_w1, gate_b1, gate_w2, gate_b2, gatew);
  k_fold1 <<<1, 256, 0, stream>>>(gat_w1, gat_as1, gat_ad1, wsd);
  k_attdotx<<<g16, 256, 0, stream>>>(xb, wsd, asrc1, adst1, NN);
  k_edgew1<<<g4, 256, 0, stream>>>(asrc1, adst1, offs, cnt, csr, wvE1, rden1, wvS1, NN);

  // ---- layer-1 one-pass pre-aggregation over xb ----
  k_aggx<<<g4, 256, 0, stream>>>(xb, wvE1, rden1, wvS1, dis, invc, offs, cnt, csr,
                                 z, agcnx, asagex, NN);

  // ---- fused: GAT1+GAT2 (y=0), GCN1 mm (y=1), SAGE1 mm (y=2) ----
  {
    FSP p = {};
    p.N = NN;
    p.z = z; p.wb1 = wb_gat1; p.b1 = gat_b1;
    p.wb2 = wb_gat2; p.as2 = gat_as2; p.ad2 = gat_ad2;
    p.h2 = h2; p.asrc2 = asrc2; p.adst2 = adst2;
    p.mm[0] = {agcnx, wb_gcn1, nullptr, nullptr, a1, gcn_b1, bn_gamma, bn_beta, 1};
    p.mm[1] = {asagex, wb_wl1, xb, wb_wr1, s1, sage_bl1, nullptr, nullptr, 3};
    k_fused1<<<dim3(gN,3), 256, 0, stream>>>(p);
  }

  k_edgew2<<<g4, 256, 0, stream>>>(asrc2, adst2, offs, cnt, csr, wvE2, rden2, wvS2, NN);

  // ---- layer-2 one-pass pre-aggregation ----
  k_aggf<<<g4, 256, 0, stream>>>(a1, s1, h2, wvE2, rden2, wvS2, dis, invc,
                                 offs, cnt, csr, A2agg, S2agg, T2, NN);

  // ---- final matmuls + gate combine ----
  k_mm_final<<<gN, 256, 0, stream>>>(A2agg, wb_gcn2, gcn_b2, S2agg, wb_wl2, sage_bl2,
                                     s1, wb_wr2, T2, gat_b2, gatew, out, NN);
}